// Round 1
// baseline (951.961 us; speedup 1.0000x reference)
//
#include <hip/hip_runtime.h>
#include <cmath>

namespace {

constexpr int BB = 8192;
constexpr int TT = 512;
constexpr int FF = 2048;
constexpr float EPS_LN  = 1e-5f;
constexpr float EPS_SIG = 1e-8f;

typedef _Float16 half8 __attribute__((ext_vector_type(8)));
typedef _Float16 half4 __attribute__((ext_vector_type(4)));
typedef float f32x4 __attribute__((ext_vector_type(4)));

typedef __attribute__((address_space(1))) void gvoid_t;
typedef __attribute__((address_space(3))) void lvoid_t;

__device__ __forceinline__ void async16(void* lds, const void* g) {
    __builtin_amdgcn_global_load_lds((gvoid_t*)g, (lvoid_t*)lds, 16, 0, 0);
}

__device__ __forceinline__ float silu_f(float v) {
    return v / (1.0f + expf(-v));
}

// ------------- fp32 -> f16 (hi, optional lo residual) weight conversion -------------
template <bool LO>
__global__ __launch_bounds__(256) void cvt_kernel(
    const float* __restrict__ s, _Float16* __restrict__ hi,
    _Float16* __restrict__ lo, int n) {
    int i = (blockIdx.x * 256 + threadIdx.x) * 4;
    if (i >= n) return;
    float4 v = *(const float4*)(s + i);
    half4 h;
    h[0] = (_Float16)v.x; h[1] = (_Float16)v.y;
    h[2] = (_Float16)v.z; h[3] = (_Float16)v.w;
    *(half4*)(hi + i) = h;
    if (LO) {
        half4 l;
        l[0] = (_Float16)(v.x - (float)h[0]);
        l[1] = (_Float16)(v.y - (float)h[1]);
        l[2] = (_Float16)(v.z - (float)h[2]);
        l[3] = (_Float16)(v.w - (float)h[3]);
        *(half4*)(lo + i) = l;
    }
}

// ---------------- tokenizer: Q[b,t] = silu(x . l1_w[t] + l1_b[t]) ----------------
__global__ __launch_bounds__(256) void tok_kernel(
    const float* __restrict__ x, const float* __restrict__ l1w,
    const float* __restrict__ l1b, float* __restrict__ Q) {
    int idx = blockIdx.x * 256 + threadIdx.x;          // < B*T
    int b = idx >> 9, t = idx & 511;
    float x0 = x[2 * b], x1 = x[2 * b + 1];
    float v = fmaf(x0, l1w[2 * t], fmaf(x1, l1w[2 * t + 1], l1b[t]));
    Q[idx] = silu_f(v);
}

// ------- layernorm (fp32 in, f16 out, optional f16 lo residual), wave per row -------
template <bool LO>
__global__ __launch_bounds__(256) void ln_kernel(
    const float* __restrict__ X, const float* __restrict__ g,
    const float* __restrict__ bia, _Float16* __restrict__ Y,
    _Float16* __restrict__ Ylo) {
    int lane = threadIdx.x & 63;
    int row  = blockIdx.x * 4 + (threadIdx.x >> 6);
    const float* xr = X + (size_t)row * TT;
    float v[8];
    {
        float4 a = *(const float4*)(xr + lane * 8);
        float4 c = *(const float4*)(xr + lane * 8 + 4);
        v[0]=a.x; v[1]=a.y; v[2]=a.z; v[3]=a.w;
        v[4]=c.x; v[5]=c.y; v[6]=c.z; v[7]=c.w;
    }
    float s = 0.f;
    #pragma unroll
    for (int i = 0; i < 8; ++i) s += v[i];
    #pragma unroll
    for (int off = 32; off > 0; off >>= 1) s += __shfl_down(s, off);
    float mean = __shfl(s, 0) * (1.0f / TT);
    float ss = 0.f;
    #pragma unroll
    for (int i = 0; i < 8; ++i) { float d = v[i] - mean; ss = fmaf(d, d, ss); }
    #pragma unroll
    for (int off = 32; off > 0; off >>= 1) ss += __shfl_down(ss, off);
    float var  = __shfl(ss, 0) * (1.0f / TT);
    float rstd = rsqrtf(var + EPS_LN);
    half8 hv, lv;
    #pragma unroll
    for (int i = 0; i < 8; ++i) {
        int t = lane * 8 + i;
        float o = (v[i] - mean) * rstd * g[t] + bia[t];
        hv[i] = (_Float16)o;
        if (LO) lv[i] = (_Float16)(o - (float)hv[i]);
    }
    *(half8*)(Y + (size_t)row * TT + lane * 8) = hv;
    if (LO) *(half8*)(Ylo + (size_t)row * TT + lane * 8) = lv;
}

// --------------- MFMA GEMM: C[M,N] = act(A[M,K] @ W[N,K]^T + b) (+R) ---------------
// BM=128, BK=32, 4 waves 2x2, wave tile 64 x (BN/2), mfma 16x16x32 f16.
// Deep-pipelined staging (T3/T4): NBUF LDS buffers, D=NBUF-1 stages in flight,
// counted s_waitcnt vmcnt((D-1)*LPS) + RAW s_barrier per K-iter -- the vmcnt
// queue is never drained to 0 in the main loop, so the per-iter HBM latency
// (~900cy) hides under D-1 compute iterations instead of stalling the barrier.
// Tail iterations peeled with descending compile-time waits (counts must be exact;
// no other VMEM ops exist inside the loop).
// Hazard: stage(k+D) overwrites buf (k-1)%NBUF, whose reads were consumed (MFMA
// operand dep) before every wave arrived at barrier k -> race-free.
// XOR chunk swizzle (source-side): store 16B-chunk c of row r at slot c^((r>>1)&3)
// -> fragment ds_read_b128 is 2-way-or-less bank aliased (free per m136).
// SPLIT: acc = A@W + Alo@W + A@Wlo (near-fp32 precision from f16 inputs).
template <int BN, int ACT, bool RESID, bool SPLIT, typename OutT>
__global__ __launch_bounds__(256) void gemm16_kernel(
    const _Float16* __restrict__ A, const _Float16* __restrict__ Alo,
    const _Float16* __restrict__ W, const _Float16* __restrict__ Wlo,
    const float* __restrict__ bias, const float* __restrict__ R,
    OutT* __restrict__ C, int N, int K) {
    constexpr int BM = 128;
    constexpr int BK = 32;
    constexpr int WN = BN / 2;
    constexpr int MI = 4;            // 64/16
    constexpr int NI = WN / 16;      // 4 (BN=128) or 2 (BN=64)
    constexpr int NS = SPLIT ? 2 : 1;
    constexpr int NBUF = SPLIT ? 3 : 4;      // LDS: split 72KB, BN=128 64KB, BN=64 48KB
    constexpr int D = NBUF - 1;              // prefetch distance (stages in flight)
    constexpr int LPS = NS * (2 + BN / 64);  // global_load_lds per thread per stage

    __shared__ alignas(16) _Float16 As[NBUF][NS][BM][BK];
    __shared__ alignas(16) _Float16 Ws[NBUF][NS][BN][BK];

    const int tid  = threadIdx.x;
    const int m0   = blockIdx.x * BM;
    const int n0   = blockIdx.y * BN;

    // staging decomposition: flat 16B chunk i = j*256+tid -> row i>>2, slot i&3
    const int sr = tid >> 2;                 // row (within 64-row round)
    const int sc = tid & 3;                  // slot
    const int scs = sc ^ ((sr >> 1) & 3);    // swizzled source chunk

    const _Float16* Ag[NS];
    const _Float16* Wg[NS];
    Ag[0] = A + (size_t)(m0 + sr) * K + scs * 8;
    Wg[0] = W + (size_t)(n0 + sr) * K + scs * 8;
    if (SPLIT) {
        Ag[1] = Alo + (size_t)(m0 + sr) * K + scs * 8;
        Wg[1] = Wlo + (size_t)(n0 + sr) * K + scs * 8;
    }

    const int wv   = tid >> 6;
    const int wm   = (wv >> 1) * 64;
    const int wn   = (wv & 1) * WN;
    const int lane = tid & 63;
    const int fr   = lane & 15;          // row/col within 16-tile
    const int q    = lane >> 4;          // logical k-chunk of fragment
    const int fk   = (q ^ ((fr >> 1) & 3)) * 8;   // swizzled LDS k-offset (halves)

    const f32x4 vzero = {0.f, 0.f, 0.f, 0.f};
    f32x4 acc[MI][NI];
    #pragma unroll
    for (int mi = 0; mi < MI; ++mi)
        #pragma unroll
        for (int ni = 0; ni < NI; ++ni) acc[mi][ni] = vzero;

    auto stage = [&](int buf, int k0) {
        #pragma unroll
        for (int s = 0; s < NS; ++s) {
            async16(&As[buf][s][sr][sc * 8], Ag[s] + k0);
            async16(&As[buf][s][64 + sr][sc * 8], Ag[s] + (size_t)64 * K + k0);
            async16(&Ws[buf][s][sr][sc * 8], Wg[s] + k0);
            if (BN == 128)
                async16(&Ws[buf][s][64 + sr][sc * 8], Wg[s] + (size_t)64 * K + k0);
        }
    };

    auto compute = [&](int buf) {
        half8 a[MI], b[NI];
        #pragma unroll
        for (int mi = 0; mi < MI; ++mi)
            a[mi] = *(const half8*)&As[buf][0][wm + mi * 16 + fr][fk];
        #pragma unroll
        for (int ni = 0; ni < NI; ++ni)
            b[ni] = *(const half8*)&Ws[buf][0][wn + ni * 16 + fr][fk];
        #pragma unroll
        for (int mi = 0; mi < MI; ++mi)
            #pragma unroll
            for (int ni = 0; ni < NI; ++ni)
                acc[mi][ni] = __builtin_amdgcn_mfma_f32_16x16x32_f16(
                    a[mi], b[ni], acc[mi][ni], 0, 0, 0);
        if (SPLIT) {
            half8 a2[MI], b2[NI];
            #pragma unroll
            for (int mi = 0; mi < MI; ++mi)
                a2[mi] = *(const half8*)&As[buf][1][wm + mi * 16 + fr][fk];
            #pragma unroll
            for (int ni = 0; ni < NI; ++ni)
                b2[ni] = *(const half8*)&Ws[buf][1][wn + ni * 16 + fr][fk];
            #pragma unroll
            for (int mi = 0; mi < MI; ++mi)
                #pragma unroll
                for (int ni = 0; ni < NI; ++ni)
                    acc[mi][ni] = __builtin_amdgcn_mfma_f32_16x16x32_f16(
                        a2[mi], b[ni], acc[mi][ni], 0, 0, 0);
            #pragma unroll
            for (int mi = 0; mi < MI; ++mi)
                #pragma unroll
                for (int ni = 0; ni < NI; ++ni)
                    acc[mi][ni] = __builtin_amdgcn_mfma_f32_16x16x32_f16(
                        a[mi], b2[ni], acc[mi][ni], 0, 0, 0);
        }
    };

    const int NK = K / BK;          // >= 16 for every instantiation (>= D+1)

    // prologue: D stages in flight
    #pragma unroll
    for (int s = 0; s < D; ++s) stage(s, s * BK);

    // main loop: own tile's loads done, (D-1)*LPS still in flight -- never drain.
    int rbuf = 0, sbuf = D;
    for (int ki = 0; ki + D <= NK; ++ki) {
        asm volatile("s_waitcnt vmcnt(%0)" :: "n"((D - 1) * LPS) : "memory");
        __builtin_amdgcn_s_barrier();
        if (ki + D < NK) {
            stage(sbuf, (ki + D) * BK);
            sbuf = (sbuf + 1 == NBUF) ? 0 : sbuf + 1;
        }
        compute(rbuf);
        rbuf = (rbuf + 1 == NBUF) ? 0 : rbuf + 1;
    }
    // peeled tail: descending exact waits
    if constexpr (D == 3) {
        asm volatile("s_waitcnt vmcnt(%0)" :: "n"(LPS) : "memory");
        __builtin_amdgcn_s_barrier();
        compute(rbuf);
        rbuf = (rbuf + 1 == NBUF) ? 0 : rbuf + 1;
    }
    asm volatile("s_waitcnt vmcnt(0)" ::: "memory");
    __builtin_amdgcn_s_barrier();
    compute(rbuf);

    // C/D layout: col = lane&15, row = (lane>>4)*4 + reg
    const int r0 = (lane >> 4) * 4;
    #pragma unroll
    for (int mi = 0; mi < MI; ++mi) {
        #pragma unroll
        for (int ni = 0; ni < NI; ++ni) {
            const int col = n0 + wn + ni * 16 + fr;
            const float bv = bias[col];
            #pragma unroll
            for (int r = 0; r < 4; ++r) {
                const int row = m0 + wm + mi * 16 + r0 + r;
                float v = acc[mi][ni][r] + bv;
                if (ACT == 1) v = silu_f(v);
                if (ACT == 2) v = tanhf(v);
                if (RESID) v += R[(size_t)row * N + col];
                C[(size_t)row * N + col] = (OutT)v;
            }
        }
    }
}

// ------- Gaussian kernelized attention update: Q += sum_k S(G,mu,sig)*H -------
__global__ __launch_bounds__(256) void attn_kernel(
    float* __restrict__ Q, const float* __restrict__ mu_,
    const float* __restrict__ sig_, const float* __restrict__ x,
    const float* __restrict__ omega, const float* __restrict__ G,
    const float* __restrict__ phase) {
    __shared__ float cs[8][260];
    __shared__ float gs[8][260];
    const int tid = threadIdx.x;
    const int b   = blockIdx.x >> 1;
    const int t0  = (blockIdx.x & 1) * 256;
    const float x0 = x[2 * b], x1 = x[2 * b + 1];
    #pragma unroll
    for (int it = 0; it < 8; ++it) {
        int j = it * 256 + tid;            // 0..2047
        int e = t0 * 8 + j;                // flat (t,k) index
        float2 om = *(const float2*)(omega + 2 * e);
        float arg = fmaf(om.x, x0, fmaf(om.y, x1, phase[e]));
        cs[j & 7][j >> 3] = __cosf(arg);
        gs[j & 7][j >> 3] = G[e];
    }
    __syncthreads();
    const int idx = blockIdx.x * 256 + tid;   // = b*512 + t0 + tid
    float mu  = mu_[idx];
    float sig = sig_[idx];
    float inv = -0.5f * __builtin_amdgcn_rcpf(fmaf(sig, sig, EPS_SIG));
    float acc = 0.f;
    #pragma unroll
    for (int k = 0; k < 8; ++k) {
        float d = gs[k][tid] - mu;
        acc = fmaf(__expf(d * d * inv), cs[k][tid], acc);
    }
    Q[idx] += acc;
}

// ---------------- readout: out[b] = silu(Q[b,:]) . ro_w + ro_b ----------------
__global__ __launch_bounds__(256) void readout_kernel(
    const float* __restrict__ Q, const float* __restrict__ row_,
    const float* __restrict__ rob, float* __restrict__ out) {
    int lane = threadIdx.x & 63;
    int row  = blockIdx.x * 4 + (threadIdx.x >> 6);
    const float* qr = Q + (size_t)row * TT;
    float acc = 0.f;
    #pragma unroll
    for (int i = 0; i < 8; ++i) {
        int t = lane * 8 + i;
        acc = fmaf(silu_f(qr[t]), row_[t], acc);
    }
    #pragma unroll
    for (int off = 32; off > 0; off >>= 1) acc += __shfl_down(acc, off);
    if (lane == 0) out[row] = acc + rob[0];
}

} // namespace

extern "C" void kernel_launch(void* const* d_in, const int* in_sizes, int n_in,
                              void* d_out, int out_size, void* d_ws, size_t ws_size,
                              hipStream_t stream) {
    const float* x     = (const float*)d_in[0];
    const float* omega = (const float*)d_in[1];
    const float* G     = (const float*)d_in[2];
    const float* phase = (const float*)d_in[3];
    const float* l1_w  = (const float*)d_in[4];
    const float* l1_b  = (const float*)d_in[5];
    const float* mu_w  = (const float*)d_in[6];
    const float* mu_b  = (const float*)d_in[7];
    const float* sg_w  = (const float*)d_in[8];
    const float* sg_b  = (const float*)d_in[9];
    const float* alqg  = (const float*)d_in[10];
    const float* alqb  = (const float*)d_in[11];
    const float* alfg  = (const float*)d_in[12];
    const float* alfb  = (const float*)d_in[13];
    const float* a_w1  = (const float*)d_in[14];
    const float* a_b1  = (const float*)d_in[15];
    const float* a_w2  = (const float*)d_in[16];
    const float* a_b2  = (const float*)d_in[17];
    const float* mln_g = (const float*)d_in[18];
    const float* mln_b = (const float*)d_in[19];
    const float* m_w1  = (const float*)d_in[20];
    const float* m_b1  = (const float*)d_in[21];
    const float* m_w2  = (const float*)d_in[22];
    const float* m_b2  = (const float*)d_in[23];
    const float* ro_w  = (const float*)d_in[24];
    const float* ro_b  = (const float*)d_in[25];

    // ---- workspace layout (total 100,663,296 B == round-1 proven footprint) ----
    char* ws = (char*)d_ws;
    float*     Q    = (float*)ws;                          // 16 MB  [B,T] fp32
    _Float16*  h_hi = (_Float16*)(ws + 16777216);          //  8 MB  [B,T] f16
    _Float16*  h_lo = (_Float16*)(ws + 25165824);          //  8 MB  [B,T] f16
    _Float16*  mid  = (_Float16*)(ws + 33554432);          // 32 MB  [B,F] f16
    float*     mu   = (float*)(ws + 33554432);             // alias on mid
    float*     sig  = (float*)(ws + 50331648);             // alias on mid
    _Float16*  wbuf = (_Float16*)(ws + 67108864);          // 32 MB  f16 weights

    _Float16* muw_hi = wbuf;                     // 4*512*512
    _Float16* muw_lo = muw_hi + 1048576;
    _Float16* sgw_hi = muw_lo + 1048576;
    _Float16* sgw_lo = sgw_hi + 1048576;
    _Float16* aw1    = sgw_lo + 1048576;         // 4*2048*512
    _Float16* aw2    = aw1 + 4194304;
    _Float16* mw1    = aw2 + 4194304;            // 2*2048*512
    _Float16* mw2    = mw1 + 2097152;

    dim3 blk(256);

    // weight conversion (re-done every call; inputs are re-poisoned by harness)
    cvt_kernel<true ><<<1024, blk, 0, stream>>>(mu_w, muw_hi, muw_lo, 1048576);
    cvt_kernel<true ><<<1024, blk, 0, stream>>>(sg_w, sgw_hi, sgw_lo, 1048576);
    cvt_kernel<false><<<4096, blk, 0, stream>>>(a_w1, aw1, nullptr, 4194304);
    cvt_kernel<false><<<4096, blk, 0, stream>>>(a_w2, aw2, nullptr, 4194304);
    cvt_kernel<false><<<2048, blk, 0, stream>>>(m_w1, mw1, nullptr, 2097152);
    cvt_kernel<false><<<2048, blk, 0, stream>>>(m_w2, mw2, nullptr, 2097152);

    tok_kernel<<<BB * TT / 256, blk, 0, stream>>>(x, l1_w, l1_b, Q);

    for (int i = 0; i < 4; ++i) {
        ln_kernel<true><<<BB / 4, blk, 0, stream>>>(
            Q, alqg + i * TT, alqb + i * TT, h_hi, h_lo);
        gemm16_kernel<64, 2, false, true, float><<<dim3(BB / 128, TT / 64), blk, 0, stream>>>(
            h_hi, h_lo, muw_hi + (size_t)i * 262144, muw_lo + (size_t)i * 262144,
            mu_b + i * TT, nullptr, mu, TT, TT);
        gemm16_kernel<64, 0, false, true, float><<<dim3(BB / 128, TT / 64), blk, 0, stream>>>(
            h_hi, h_lo, sgw_hi + (size_t)i * 262144, sgw_lo + (size_t)i * 262144,
            sg_b + i * TT, nullptr, sig, TT, TT);
        attn_kernel<<<BB * TT / 256, blk, 0, stream>>>(Q, mu, sig, x, omega, G, phase);
        ln_kernel<false><<<BB / 4, blk, 0, stream>>>(
            Q, alfg + i * TT, alfb + i * TT, h_hi, nullptr);
        gemm16_kernel<128, 1, false, false, _Float16><<<dim3(BB / 128, FF / 128), blk, 0, stream>>>(
            h_hi, nullptr, aw1 + (size_t)i * 1048576, nullptr,
            a_b1 + i * FF, nullptr, mid, FF, TT);
        gemm16_kernel<64, 0, true, false, float><<<dim3(BB / 128, TT / 64), blk, 0, stream>>>(
            mid, nullptr, aw2 + (size_t)i * 1048576, nullptr,
            a_b2 + i * TT, Q, Q, TT, FF);
    }
    for (int i = 0; i < 2; ++i) {
        ln_kernel<false><<<BB / 4, blk, 0, stream>>>(
            Q, mln_g + i * TT, mln_b + i * TT, h_hi, nullptr);
        gemm16_kernel<128, 1, false, false, _Float16><<<dim3(BB / 128, FF / 128), blk, 0, stream>>>(
            h_hi, nullptr, mw1 + (size_t)i * 1048576, nullptr,
            m_b1 + i * FF, nullptr, mid, FF, TT);
        gemm16_kernel<64, 0, true, false, float><<<dim3(BB / 128, TT / 64), blk, 0, stream>>>(
            mid, nullptr, mw2 + (size_t)i * 1048576, nullptr,
            m_b2 + i * TT, Q, Q, TT, FF);
    }

    readout_kernel<<<BB / 4, blk, 0, stream>>>(Q, ro_w, ro_b, (float*)d_out);
}

// Round 2
// 897.420 us; speedup vs baseline: 1.0608x; 1.0608x over previous
//
#include <hip/hip_runtime.h>
#include <cmath>

namespace {

constexpr int BB = 8192;
constexpr int TT = 512;
constexpr int FF = 2048;
constexpr float EPS_LN  = 1e-5f;
constexpr float EPS_SIG = 1e-8f;

typedef _Float16 half8 __attribute__((ext_vector_type(8)));
typedef _Float16 half4 __attribute__((ext_vector_type(4)));
typedef float f32x4 __attribute__((ext_vector_type(4)));

typedef __attribute__((address_space(1))) void gvoid_t;
typedef __attribute__((address_space(3))) void lvoid_t;

__device__ __forceinline__ void async16(void* lds, const void* g) {
    __builtin_amdgcn_global_load_lds((gvoid_t*)g, (lvoid_t*)lds, 16, 0, 0);
}

__device__ __forceinline__ float silu_f(float v) {
    return v / (1.0f + expf(-v));
}
// fast silu: only for f16-rounded outputs (error ~1e-6 << f16 ulp)
__device__ __forceinline__ float silu_fast(float v) {
    return v * __builtin_amdgcn_rcpf(1.0f + __expf(-v));
}

// ------------- fp32 -> f16 (hi, optional lo residual) weight conversion -------------
template <bool LO>
__global__ __launch_bounds__(256) void cvt_kernel(
    const float* __restrict__ s, _Float16* __restrict__ hi,
    _Float16* __restrict__ lo, int n) {
    int i = (blockIdx.x * 256 + threadIdx.x) * 4;
    if (i >= n) return;
    float4 v = *(const float4*)(s + i);
    half4 h;
    h[0] = (_Float16)v.x; h[1] = (_Float16)v.y;
    h[2] = (_Float16)v.z; h[3] = (_Float16)v.w;
    *(half4*)(hi + i) = h;
    if (LO) {
        half4 l;
        l[0] = (_Float16)(v.x - (float)h[0]);
        l[1] = (_Float16)(v.y - (float)h[1]);
        l[2] = (_Float16)(v.z - (float)h[2]);
        l[3] = (_Float16)(v.w - (float)h[3]);
        *(half4*)(lo + i) = l;
    }
}

// ---- cvt into mu/sig-concatenated layout: src [4][512][512] -> dst [4][1024][512]+base ----
__global__ __launch_bounds__(256) void cvtcat_kernel(
    const float* __restrict__ s, _Float16* __restrict__ hi,
    _Float16* __restrict__ lo, int base) {
    int i = (blockIdx.x * 256 + threadIdx.x) * 4;          // < 4*512*512
    int dst = ((i >> 18) << 19) + base + (i & 262143);
    float4 v = *(const float4*)(s + i);
    half4 h, l;
    h[0] = (_Float16)v.x; h[1] = (_Float16)v.y;
    h[2] = (_Float16)v.z; h[3] = (_Float16)v.w;
    l[0] = (_Float16)(v.x - (float)h[0]);
    l[1] = (_Float16)(v.y - (float)h[1]);
    l[2] = (_Float16)(v.z - (float)h[2]);
    l[3] = (_Float16)(v.w - (float)h[3]);
    *(half4*)(hi + dst) = h;
    *(half4*)(lo + dst) = l;
}

// ---------------- tokenizer: Q[b,t] = silu(x . l1_w[t] + l1_b[t]) ----------------
__global__ __launch_bounds__(256) void tok_kernel(
    const float* __restrict__ x, const float* __restrict__ l1w,
    const float* __restrict__ l1b, float* __restrict__ Q) {
    int idx = blockIdx.x * 256 + threadIdx.x;          // < B*T
    int b = idx >> 9, t = idx & 511;
    float x0 = x[2 * b], x1 = x[2 * b + 1];
    float v = fmaf(x0, l1w[2 * t], fmaf(x1, l1w[2 * t + 1], l1b[t]));
    Q[idx] = silu_f(v);
}

// ------- layernorm (fp32 in, f16 out, optional f16 lo residual), wave per row -------
template <bool LO>
__global__ __launch_bounds__(256) void ln_kernel(
    const float* __restrict__ X, const float* __restrict__ g,
    const float* __restrict__ bia, _Float16* __restrict__ Y,
    _Float16* __restrict__ Ylo) {
    int lane = threadIdx.x & 63;
    int row  = blockIdx.x * 4 + (threadIdx.x >> 6);
    const float* xr = X + (size_t)row * TT;
    float v[8];
    {
        float4 a = *(const float4*)(xr + lane * 8);
        float4 c = *(const float4*)(xr + lane * 8 + 4);
        v[0]=a.x; v[1]=a.y; v[2]=a.z; v[3]=a.w;
        v[4]=c.x; v[5]=c.y; v[6]=c.z; v[7]=c.w;
    }
    float s = 0.f;
    #pragma unroll
    for (int i = 0; i < 8; ++i) s += v[i];
    #pragma unroll
    for (int off = 32; off > 0; off >>= 1) s += __shfl_down(s, off);
    float mean = __shfl(s, 0) * (1.0f / TT);
    float ss = 0.f;
    #pragma unroll
    for (int i = 0; i < 8; ++i) { float d = v[i] - mean; ss = fmaf(d, d, ss); }
    #pragma unroll
    for (int off = 32; off > 0; off >>= 1) ss += __shfl_down(ss, off);
    float var  = __shfl(ss, 0) * (1.0f / TT);
    float rstd = rsqrtf(var + EPS_LN);
    half8 hv, lv;
    #pragma unroll
    for (int i = 0; i < 8; ++i) {
        int t = lane * 8 + i;
        float o = (v[i] - mean) * rstd * g[t] + bia[t];
        hv[i] = (_Float16)o;
        if (LO) lv[i] = (_Float16)(o - (float)hv[i]);
    }
    *(half8*)(Y + (size_t)row * TT + lane * 8) = hv;
    if (LO) *(half8*)(Ylo + (size_t)row * TT + lane * 8) = lv;
}

// --------------- MFMA GEMM: C[M,N] = act(A[M,K] @ W[N,K]^T + b) (+R) ---------------
// BM=128, BK=32, 4 waves 2x2, wave tile 64 x (BN/2), mfma 16x16x32 f16.
// NBUF LDS buffers, D=NBUF-1 stages in flight, counted s_waitcnt vmcnt + raw
// s_barrier per K-iter. NBUF chosen to keep LDS <= 48KB (3 blocks/CU residency).
// XOR chunk swizzle (source-side): store 16B-chunk c of row r at slot c^((r>>1)&3)
// -> fragment ds_read_b128 is 2-way-or-less bank aliased (free per m136).
// SPLIT: acc = A@W + Alo@W + A@Wlo (near-fp32 precision from f16 inputs).
// ACT: 0=none, 1=silu(fast, f16-out), 2=tanh, 3=tanh for cols<nsplit else none.
// bias: cols<nsplit from bias[], else bias2[col-nsplit] (block-uniform select).
template <int BN, int ACT, bool RESID, bool SPLIT, typename OutT>
__global__ __launch_bounds__(256) void gemm16_kernel(
    const _Float16* __restrict__ A, const _Float16* __restrict__ Alo,
    const _Float16* __restrict__ W, const _Float16* __restrict__ Wlo,
    const float* __restrict__ bias, const float* __restrict__ bias2,
    const float* __restrict__ R,
    OutT* __restrict__ C, int N, int K, int nsplit) {
    constexpr int BM = 128;
    constexpr int BK = 32;
    constexpr int WN = BN / 2;
    constexpr int MI = 4;            // 64/16
    constexpr int NI = WN / 16;      // 4 (BN=128) or 2 (BN=64)
    constexpr int NS = SPLIT ? 2 : 1;
    constexpr int NBUF = SPLIT ? 2 : 3;      // LDS: split 48KB, BN=128 48KB, BN=64 36KB
    constexpr int D = NBUF - 1;              // prefetch distance (stages in flight)
    constexpr int LPS = NS * (2 + BN / 64);  // global_load_lds per thread per stage

    __shared__ alignas(16) _Float16 As[NBUF][NS][BM][BK];
    __shared__ alignas(16) _Float16 Ws[NBUF][NS][BN][BK];

    const int tid  = threadIdx.x;
    const int m0   = blockIdx.x * BM;
    const int n0   = blockIdx.y * BN;

    // staging decomposition: flat 16B chunk i = j*256+tid -> row i>>2, slot i&3
    const int sr = tid >> 2;                 // row (within 64-row round)
    const int sc = tid & 3;                  // slot
    const int scs = sc ^ ((sr >> 1) & 3);    // swizzled source chunk

    const _Float16* Ag[NS];
    const _Float16* Wg[NS];
    Ag[0] = A + (size_t)(m0 + sr) * K + scs * 8;
    Wg[0] = W + (size_t)(n0 + sr) * K + scs * 8;
    if (SPLIT) {
        Ag[1] = Alo + (size_t)(m0 + sr) * K + scs * 8;
        Wg[1] = Wlo + (size_t)(n0 + sr) * K + scs * 8;
    }

    const int wv   = tid >> 6;
    const int wm   = (wv >> 1) * 64;
    const int wn   = (wv & 1) * WN;
    const int lane = tid & 63;
    const int fr   = lane & 15;          // row/col within 16-tile
    const int q    = lane >> 4;          // logical k-chunk of fragment
    const int fk   = (q ^ ((fr >> 1) & 3)) * 8;   // swizzled LDS k-offset (halves)

    const f32x4 vzero = {0.f, 0.f, 0.f, 0.f};
    f32x4 acc[MI][NI];
    #pragma unroll
    for (int mi = 0; mi < MI; ++mi)
        #pragma unroll
        for (int ni = 0; ni < NI; ++ni) acc[mi][ni] = vzero;

    auto stage = [&](int buf, int k0) {
        #pragma unroll
        for (int s = 0; s < NS; ++s) {
            async16(&As[buf][s][sr][sc * 8], Ag[s] + k0);
            async16(&As[buf][s][64 + sr][sc * 8], Ag[s] + (size_t)64 * K + k0);
            async16(&Ws[buf][s][sr][sc * 8], Wg[s] + k0);
            if (BN == 128)
                async16(&Ws[buf][s][64 + sr][sc * 8], Wg[s] + (size_t)64 * K + k0);
        }
    };

    auto compute = [&](int buf) {
        half8 a[MI], b[NI];
        #pragma unroll
        for (int mi = 0; mi < MI; ++mi)
            a[mi] = *(const half8*)&As[buf][0][wm + mi * 16 + fr][fk];
        #pragma unroll
        for (int ni = 0; ni < NI; ++ni)
            b[ni] = *(const half8*)&Ws[buf][0][wn + ni * 16 + fr][fk];
        #pragma unroll
        for (int mi = 0; mi < MI; ++mi)
            #pragma unroll
            for (int ni = 0; ni < NI; ++ni)
                acc[mi][ni] = __builtin_amdgcn_mfma_f32_16x16x32_f16(
                    a[mi], b[ni], acc[mi][ni], 0, 0, 0);
        if (SPLIT) {
            half8 a2[MI], b2[NI];
            #pragma unroll
            for (int mi = 0; mi < MI; ++mi)
                a2[mi] = *(const half8*)&As[buf][1][wm + mi * 16 + fr][fk];
            #pragma unroll
            for (int ni = 0; ni < NI; ++ni)
                b2[ni] = *(const half8*)&Ws[buf][1][wn + ni * 16 + fr][fk];
            #pragma unroll
            for (int mi = 0; mi < MI; ++mi)
                #pragma unroll
                for (int ni = 0; ni < NI; ++ni)
                    acc[mi][ni] = __builtin_amdgcn_mfma_f32_16x16x32_f16(
                        a2[mi], b[ni], acc[mi][ni], 0, 0, 0);
            #pragma unroll
            for (int mi = 0; mi < MI; ++mi)
                #pragma unroll
                for (int ni = 0; ni < NI; ++ni)
                    acc[mi][ni] = __builtin_amdgcn_mfma_f32_16x16x32_f16(
                        a[mi], b2[ni], acc[mi][ni], 0, 0, 0);
        }
    };

    const int NK = K / BK;          // >= 16 for every instantiation (> D)

    // prologue: D stages in flight
    #pragma unroll
    for (int s = 0; s < D; ++s) stage(s, s * BK);

    int rbuf = 0, sbuf = D;
    for (int ki = 0; ki < NK - D; ++ki) {
        asm volatile("s_waitcnt vmcnt(%0)" :: "n"((D - 1) * LPS) : "memory");
        __builtin_amdgcn_s_barrier();
        stage(sbuf, (ki + D) * BK);
        sbuf = (sbuf + 1 == NBUF) ? 0 : sbuf + 1;
        compute(rbuf);
        rbuf = (rbuf + 1 == NBUF) ? 0 : rbuf + 1;
    }
    // epilogue: drain remaining D tiles with descending exact waits
    if constexpr (D >= 3) {
        asm volatile("s_waitcnt vmcnt(%0)" :: "n"(2 * LPS) : "memory");
        __builtin_amdgcn_s_barrier();
        compute(rbuf);
        rbuf = (rbuf + 1 == NBUF) ? 0 : rbuf + 1;
    }
    if constexpr (D >= 2) {
        asm volatile("s_waitcnt vmcnt(%0)" :: "n"(1 * LPS) : "memory");
        __builtin_amdgcn_s_barrier();
        compute(rbuf);
        rbuf = (rbuf + 1 == NBUF) ? 0 : rbuf + 1;
    }
    asm volatile("s_waitcnt vmcnt(0)" ::: "memory");
    __builtin_amdgcn_s_barrier();
    compute(rbuf);

    // C/D layout: col = lane&15, row = (lane>>4)*4 + reg
    const bool fh = (n0 < nsplit);                 // block-uniform half select
    const float* bp = fh ? bias : bias2;
    const int coff = fh ? 0 : nsplit;
    const int r0 = (lane >> 4) * 4;
    #pragma unroll
    for (int mi = 0; mi < MI; ++mi) {
        #pragma unroll
        for (int ni = 0; ni < NI; ++ni) {
            const int col = n0 + wn + ni * 16 + fr;
            const float bv = bp[col - coff];
            #pragma unroll
            for (int r = 0; r < 4; ++r) {
                const int row = m0 + wm + mi * 16 + r0 + r;
                float v = acc[mi][ni][r] + bv;
                if (ACT == 1) v = silu_fast(v);
                if (ACT == 2) v = tanhf(v);
                if (ACT == 3 && fh) v = tanhf(v);
                if (RESID) v += R[(size_t)row * N + col];
                C[(size_t)row * N + col] = (OutT)v;
            }
        }
    }
}

// ------- Gaussian kernelized attention update: Q += sum_k S(G,mu,sig)*H -------
// MS is the fused [B,1024] buffer: cols 0..511 = mu, 512..1023 = sig.
__global__ __launch_bounds__(256) void attn_kernel(
    float* __restrict__ Q, const float* __restrict__ MS,
    const float* __restrict__ x,
    const float* __restrict__ omega, const float* __restrict__ G,
    const float* __restrict__ phase) {
    __shared__ float cs[8][260];
    __shared__ float gs[8][260];
    const int tid = threadIdx.x;
    const int b   = blockIdx.x >> 1;
    const int t0  = (blockIdx.x & 1) * 256;
    const float x0 = x[2 * b], x1 = x[2 * b + 1];
    #pragma unroll
    for (int it = 0; it < 8; ++it) {
        int j = it * 256 + tid;            // 0..2047
        int e = t0 * 8 + j;                // flat (t,k) index
        float2 om = *(const float2*)(omega + 2 * e);
        float arg = fmaf(om.x, x0, fmaf(om.y, x1, phase[e]));
        cs[j & 7][j >> 3] = __cosf(arg);
        gs[j & 7][j >> 3] = G[e];
    }
    __syncthreads();
    const int t   = t0 + tid;
    const int idx = blockIdx.x * 256 + tid;   // = b*512 + t
    float mu  = MS[(size_t)b * 1024 + t];
    float sig = MS[(size_t)b * 1024 + 512 + t];
    float inv = -0.5f * __builtin_amdgcn_rcpf(fmaf(sig, sig, EPS_SIG));
    float acc = 0.f;
    #pragma unroll
    for (int k = 0; k < 8; ++k) {
        float d = gs[k][tid] - mu;
        acc = fmaf(__expf(d * d * inv), cs[k][tid], acc);
    }
    Q[idx] += acc;
}

// ---------------- readout: out[b] = silu(Q[b,:]) . ro_w + ro_b ----------------
__global__ __launch_bounds__(256) void readout_kernel(
    const float* __restrict__ Q, const float* __restrict__ row_,
    const float* __restrict__ rob, float* __restrict__ out) {
    int lane = threadIdx.x & 63;
    int row  = blockIdx.x * 4 + (threadIdx.x >> 6);
    const float* qr = Q + (size_t)row * TT;
    float acc = 0.f;
    #pragma unroll
    for (int i = 0; i < 8; ++i) {
        int t = lane * 8 + i;
        acc = fmaf(silu_f(qr[t]), row_[t], acc);
    }
    #pragma unroll
    for (int off = 32; off > 0; off >>= 1) acc += __shfl_down(acc, off);
    if (lane == 0) out[row] = acc + rob[0];
}

} // namespace

extern "C" void kernel_launch(void* const* d_in, const int* in_sizes, int n_in,
                              void* d_out, int out_size, void* d_ws, size_t ws_size,
                              hipStream_t stream) {
    const float* x     = (const float*)d_in[0];
    const float* omega = (const float*)d_in[1];
    const float* G     = (const float*)d_in[2];
    const float* phase = (const float*)d_in[3];
    const float* l1_w  = (const float*)d_in[4];
    const float* l1_b  = (const float*)d_in[5];
    const float* mu_w  = (const float*)d_in[6];
    const float* mu_b  = (const float*)d_in[7];
    const float* sg_w  = (const float*)d_in[8];
    const float* sg_b  = (const float*)d_in[9];
    const float* alqg  = (const float*)d_in[10];
    const float* alqb  = (const float*)d_in[11];
    const float* alfg  = (const float*)d_in[12];
    const float* alfb  = (const float*)d_in[13];
    const float* a_w1  = (const float*)d_in[14];
    const float* a_b1  = (const float*)d_in[15];
    const float* a_w2  = (const float*)d_in[16];
    const float* a_b2  = (const float*)d_in[17];
    const float* mln_g = (const float*)d_in[18];
    const float* mln_b = (const float*)d_in[19];
    const float* m_w1  = (const float*)d_in[20];
    const float* m_b1  = (const float*)d_in[21];
    const float* m_w2  = (const float*)d_in[22];
    const float* m_b2  = (const float*)d_in[23];
    const float* ro_w  = (const float*)d_in[24];
    const float* ro_b  = (const float*)d_in[25];

    // ---- workspace layout (total 100,663,296 B == round-1 proven footprint) ----
    char* ws = (char*)d_ws;
    float*     Q    = (float*)ws;                          // 16 MB  [B,T] fp32
    _Float16*  h_hi = (_Float16*)(ws + 16777216);          //  8 MB  [B,T] f16
    _Float16*  h_lo = (_Float16*)(ws + 25165824);          //  8 MB  [B,T] f16
    _Float16*  mid  = (_Float16*)(ws + 33554432);          // 32 MB  [B,F] f16
    float*     MS   = (float*)(ws + 33554432);             // alias on mid: [B,1024] fp32
    _Float16*  wbuf = (_Float16*)(ws + 67108864);          // 32 MB  f16 weights

    _Float16* msw_hi = wbuf;                     // 4*1024*512 (mu/sig concat)
    _Float16* msw_lo = msw_hi + 2097152;
    _Float16* aw1    = msw_lo + 2097152;         // 4*2048*512
    _Float16* aw2    = aw1 + 4194304;
    _Float16* mw1    = aw2 + 4194304;            // 2*2048*512
    _Float16* mw2    = mw1 + 2097152;

    dim3 blk(256);
    const int BIG = 1 << 30;

    // weight conversion (re-done every call; inputs are re-poisoned by harness)
    cvtcat_kernel<<<1024, blk, 0, stream>>>(mu_w, msw_hi, msw_lo, 0);
    cvtcat_kernel<<<1024, blk, 0, stream>>>(sg_w, msw_hi, msw_lo, 262144);
    cvt_kernel<false><<<4096, blk, 0, stream>>>(a_w1, aw1, nullptr, 4194304);
    cvt_kernel<false><<<4096, blk, 0, stream>>>(a_w2, aw2, nullptr, 4194304);
    cvt_kernel<false><<<2048, blk, 0, stream>>>(m_w1, mw1, nullptr, 2097152);
    cvt_kernel<false><<<2048, blk, 0, stream>>>(m_w2, mw2, nullptr, 2097152);

    tok_kernel<<<BB * TT / 256, blk, 0, stream>>>(x, l1_w, l1_b, Q);

    for (int i = 0; i < 4; ++i) {
        ln_kernel<true><<<BB / 4, blk, 0, stream>>>(
            Q, alqg + i * TT, alqb + i * TT, h_hi, h_lo);
        // fused mu|sig GEMM: N=1024, tanh on mu half only
        gemm16_kernel<64, 3, false, true, float><<<dim3(BB / 128, 1024 / 64), blk, 0, stream>>>(
            h_hi, h_lo, msw_hi + (size_t)i * 524288, msw_lo + (size_t)i * 524288,
            mu_b + i * TT, sg_b + i * TT, nullptr, MS, 1024, TT, TT);
        attn_kernel<<<BB * TT / 256, blk, 0, stream>>>(Q, MS, x, omega, G, phase);
        ln_kernel<false><<<BB / 4, blk, 0, stream>>>(
            Q, alfg + i * TT, alfb + i * TT, h_hi, nullptr);
        gemm16_kernel<128, 1, false, false, _Float16><<<dim3(BB / 128, FF / 128), blk, 0, stream>>>(
            h_hi, nullptr, aw1 + (size_t)i * 1048576, nullptr,
            a_b1 + i * FF, a_b1 + i * FF, nullptr, mid, FF, TT, BIG);
        gemm16_kernel<64, 0, true, false, float><<<dim3(BB / 128, TT / 64), blk, 0, stream>>>(
            mid, nullptr, aw2 + (size_t)i * 1048576, nullptr,
            a_b2 + i * TT, a_b2 + i * TT, Q, Q, TT, FF, BIG);
    }
    for (int i = 0; i < 2; ++i) {
        ln_kernel<false><<<BB / 4, blk, 0, stream>>>(
            Q, mln_g + i * TT, mln_b + i * TT, h_hi, nullptr);
        gemm16_kernel<128, 1, false, false, _Float16><<<dim3(BB / 128, FF / 128), blk, 0, stream>>>(
            h_hi, nullptr, mw1 + (size_t)i * 1048576, nullptr,
            m_b1 + i * FF, m_b1 + i * FF, nullptr, mid, FF, TT, BIG);
        gemm16_kernel<64, 0, true, false, float><<<dim3(BB / 128, TT / 64), blk, 0, stream>>>(
            mid, nullptr, mw2 + (size_t)i * 1048576, nullptr,
            m_b2 + i * TT, m_b2 + i * TT, Q, Q, TT, FF, BIG);
    }

    readout_kernel<<<BB / 4, blk, 0, stream>>>(Q, ro_w, ro_b, (float*)d_out);
}

// Round 3
// 855.027 us; speedup vs baseline: 1.1134x; 1.0496x over previous
//
#include <hip/hip_runtime.h>
#include <cmath>

namespace {

constexpr int BB = 8192;
constexpr int TT = 512;
constexpr int FF = 2048;
constexpr float EPS_LN  = 1e-5f;
constexpr float EPS_SIG = 1e-8f;

typedef _Float16 half8 __attribute__((ext_vector_type(8)));
typedef _Float16 half4 __attribute__((ext_vector_type(4)));
typedef float f32x4 __attribute__((ext_vector_type(4)));

typedef __attribute__((address_space(1))) void gvoid_t;
typedef __attribute__((address_space(3))) void lvoid_t;

__device__ __forceinline__ void async16(void* lds, const void* g) {
    __builtin_amdgcn_global_load_lds((gvoid_t*)g, (lvoid_t*)lds, 16, 0, 0);
}

__device__ __forceinline__ float silu_f(float v) {
    return v / (1.0f + expf(-v));
}
// fast silu: only for f16-rounded outputs (error ~1e-6 << f16 ulp)
__device__ __forceinline__ float silu_fast(float v) {
    return v * __builtin_amdgcn_rcpf(1.0f + __expf(-v));
}

// ------------- fp32 -> f16 (hi, optional lo residual) weight conversion -------------
template <bool LO>
__global__ __launch_bounds__(256) void cvt_kernel(
    const float* __restrict__ s, _Float16* __restrict__ hi,
    _Float16* __restrict__ lo, int n) {
    int i = (blockIdx.x * 256 + threadIdx.x) * 4;
    if (i >= n) return;
    float4 v = *(const float4*)(s + i);
    half4 h;
    h[0] = (_Float16)v.x; h[1] = (_Float16)v.y;
    h[2] = (_Float16)v.z; h[3] = (_Float16)v.w;
    *(half4*)(hi + i) = h;
    if (LO) {
        half4 l;
        l[0] = (_Float16)(v.x - (float)h[0]);
        l[1] = (_Float16)(v.y - (float)h[1]);
        l[2] = (_Float16)(v.z - (float)h[2]);
        l[3] = (_Float16)(v.w - (float)h[3]);
        *(half4*)(lo + i) = l;
    }
}

// ---- cvt into mu/sig-concatenated layout: src [4][512][512] -> dst [4][1024][512]+base ----
__global__ __launch_bounds__(256) void cvtcat_kernel(
    const float* __restrict__ s, _Float16* __restrict__ hi,
    _Float16* __restrict__ lo, int base) {
    int i = (blockIdx.x * 256 + threadIdx.x) * 4;          // < 4*512*512
    int dst = ((i >> 18) << 19) + base + (i & 262143);
    float4 v = *(const float4*)(s + i);
    half4 h, l;
    h[0] = (_Float16)v.x; h[1] = (_Float16)v.y;
    h[2] = (_Float16)v.z; h[3] = (_Float16)v.w;
    l[0] = (_Float16)(v.x - (float)h[0]);
    l[1] = (_Float16)(v.y - (float)h[1]);
    l[2] = (_Float16)(v.z - (float)h[2]);
    l[3] = (_Float16)(v.w - (float)h[3]);
    *(half4*)(hi + dst) = h;
    *(half4*)(lo + dst) = l;
}

// ---------------- tokenizer: Q[b,t] = silu(x . l1_w[t] + l1_b[t]) ----------------
__global__ __launch_bounds__(256) void tok_kernel(
    const float* __restrict__ x, const float* __restrict__ l1w,
    const float* __restrict__ l1b, float* __restrict__ Q) {
    int idx = blockIdx.x * 256 + threadIdx.x;          // < B*T
    int b = idx >> 9, t = idx & 511;
    float x0 = x[2 * b], x1 = x[2 * b + 1];
    float v = fmaf(x0, l1w[2 * t], fmaf(x1, l1w[2 * t + 1], l1b[t]));
    Q[idx] = silu_f(v);
}

// ------- layernorm (fp32 in, f16 out, optional f16 lo residual), wave per row -------
template <bool LO>
__global__ __launch_bounds__(256) void ln_kernel(
    const float* __restrict__ X, const float* __restrict__ g,
    const float* __restrict__ bia, _Float16* __restrict__ Y,
    _Float16* __restrict__ Ylo) {
    int lane = threadIdx.x & 63;
    int row  = blockIdx.x * 4 + (threadIdx.x >> 6);
    const float* xr = X + (size_t)row * TT;
    float v[8];
    {
        float4 a = *(const float4*)(xr + lane * 8);
        float4 c = *(const float4*)(xr + lane * 8 + 4);
        v[0]=a.x; v[1]=a.y; v[2]=a.z; v[3]=a.w;
        v[4]=c.x; v[5]=c.y; v[6]=c.z; v[7]=c.w;
    }
    float s = 0.f;
    #pragma unroll
    for (int i = 0; i < 8; ++i) s += v[i];
    #pragma unroll
    for (int off = 32; off > 0; off >>= 1) s += __shfl_down(s, off);
    float mean = __shfl(s, 0) * (1.0f / TT);
    float ss = 0.f;
    #pragma unroll
    for (int i = 0; i < 8; ++i) { float d = v[i] - mean; ss = fmaf(d, d, ss); }
    #pragma unroll
    for (int off = 32; off > 0; off >>= 1) ss += __shfl_down(ss, off);
    float var  = __shfl(ss, 0) * (1.0f / TT);
    float rstd = rsqrtf(var + EPS_LN);
    half8 hv, lv;
    #pragma unroll
    for (int i = 0; i < 8; ++i) {
        int t = lane * 8 + i;
        float o = (v[i] - mean) * rstd * g[t] + bia[t];
        hv[i] = (_Float16)o;
        if (LO) lv[i] = (_Float16)(o - (float)hv[i]);
    }
    *(half8*)(Y + (size_t)row * TT + lane * 8) = hv;
    if (LO) *(half8*)(Ylo + (size_t)row * TT + lane * 8) = lv;
}

// ======== 256x256-tile deep-pipelined GEMM (T3+T4+T5): C = silu(A@W^T+b), f16 out =====
// 512 threads = 8 waves (2M x 4N), wave tile 128x64, BK=32, mfma 16x16x32.
// LDS ring of 4 K-tile buffers (A 4x[256][32] + W 4x[256][32] f16 = 128 KB).
// Steady state: vmcnt(8) -- 2 future tiles (8 wave-loads) ALWAYS in flight, never
// drained; ONE raw s_barrier per K-iter; setprio(1) around the 32-MFMA cluster.
// Lead = 3 iters (~1900 cy) > HBM latency (~900 cy).
// Hazards: stage(t+3) targets buf (t-1)&3, last read at iter t-1 before barrier t
// (ds_read completion enforced by lgkmcnt before that iter's MFMAs). Read of tile t
// is safe: own vmcnt(8) retires own tile-t loads, barrier publishes all waves'.
// Source-side XOR chunk swizzle (same scheme as gemm16, measured 0 bank conflicts).
__global__ __launch_bounds__(512) void gemm256_kernel(
    const _Float16* __restrict__ A, const _Float16* __restrict__ W,
    const float* __restrict__ bias, _Float16* __restrict__ C, int N, int K) {
    constexpr int BK   = 32;             // halves per K-tile
    constexpr int NBUF = 4;
    constexpr int BUFH = 256 * BK;       // halves per buf region (8192)

    __shared__ alignas(16) _Float16 lds[2 * NBUF * BUFH];   // 131072 B

    const int tid = threadIdx.x;
    const int m0  = blockIdx.x * 256;
    const int n0  = blockIdx.y * 256;

    // ---- staging: 4 loads/thread/tile; flat chunk idx = j*512+tid, A if idx<1024 ----
    // chunk ch of matrix: row = ch>>2, slot = ch&3; source chunk = slot ^ ((row>>1)&3)
    // LDS dest is linear in tid (wave-uniform base + lane*16  -- required by HW).
    const _Float16* gsrc[4];
    int ldsoff[4];                        // halves, within buf 0
    #pragma unroll
    for (int j = 0; j < 4; ++j) {
        int idx = j * 512 + tid;
        int isW = idx >> 10;
        int ch  = idx & 1023;
        int row = ch >> 2, sl = ch & 3;
        int src = sl ^ ((row >> 1) & 3);
        const _Float16* base = isW ? (W + (size_t)(n0 + row) * K)
                                   : (A + (size_t)(m0 + row) * K);
        gsrc[j]   = base + src * 8;
        ldsoff[j] = isW * (NBUF * BUFH) + ch * 8;
    }

    auto stage = [&](int buf, int k0) {
        #pragma unroll
        for (int j = 0; j < 4; ++j)
            async16(&lds[ldsoff[j] + buf * BUFH], gsrc[j] + k0);
    };

    // ---- fragment geometry ----
    const int wid  = tid >> 6;
    const int wr   = wid >> 2;           // 0..1  (M half)
    const int wc   = wid & 3;            // 0..3  (N quarter)
    const int lane = tid & 63;
    const int fr   = lane & 15;
    const int q    = lane >> 4;
    const int swz  = (q ^ ((fr >> 1) & 3)) * 8;   // swizzled k-chunk (halves)

    const _Float16* aBase = &lds[(wr * 128 + fr) * BK + swz];
    const _Float16* bBase = &lds[NBUF * BUFH + (wc * 64 + fr) * BK + swz];

    const f32x4 vzero = {0.f, 0.f, 0.f, 0.f};
    f32x4 acc[8][4];
    #pragma unroll
    for (int mi = 0; mi < 8; ++mi)
        #pragma unroll
        for (int ni = 0; ni < 4; ++ni) acc[mi][ni] = vzero;

    auto body = [&](int t) {
        const int d = (t & 3) * BUFH;
        half8 a[8], b[4];
        #pragma unroll
        for (int mi = 0; mi < 8; ++mi)
            a[mi] = *(const half8*)(aBase + d + mi * 16 * BK);
        #pragma unroll
        for (int ni = 0; ni < 4; ++ni)
            b[ni] = *(const half8*)(bBase + d + ni * 16 * BK);
        __builtin_amdgcn_s_setprio(1);
        #pragma unroll
        for (int mi = 0; mi < 8; ++mi)
            #pragma unroll
            for (int ni = 0; ni < 4; ++ni)
                acc[mi][ni] = __builtin_amdgcn_mfma_f32_16x16x32_f16(
                    a[mi], b[ni], acc[mi][ni], 0, 0, 0);
        __builtin_amdgcn_s_setprio(0);
    };

    const int NK = K / BK;               // 16 for K=512

    stage(0, 0); stage(1, BK); stage(2, 2 * BK);

    for (int t = 0; t < NK - 2; ++t) {
        asm volatile("s_waitcnt vmcnt(8)" ::: "memory");
        __builtin_amdgcn_s_barrier();
        asm volatile("" ::: "memory");                  // no LDS op crosses the barrier
        if (t + 3 < NK) stage((t + 3) & 3, (t + 3) * BK);
        body(t);
    }
    asm volatile("s_waitcnt vmcnt(4)" ::: "memory");
    __builtin_amdgcn_s_barrier();
    asm volatile("" ::: "memory");
    body(NK - 2);
    asm volatile("s_waitcnt vmcnt(0)" ::: "memory");
    __builtin_amdgcn_s_barrier();
    asm volatile("" ::: "memory");
    body(NK - 1);

    // C/D layout: col = lane&15, row = (lane>>4)*4 + reg
    const int r0 = q * 4;
    #pragma unroll
    for (int mi = 0; mi < 8; ++mi) {
        #pragma unroll
        for (int ni = 0; ni < 4; ++ni) {
            const int col = n0 + wc * 64 + ni * 16 + fr;
            const float bv = bias[col];
            #pragma unroll
            for (int r = 0; r < 4; ++r) {
                const int row = m0 + wr * 128 + mi * 16 + r0 + r;
                C[(size_t)row * N + col] = (_Float16)silu_fast(acc[mi][ni][r] + bv);
            }
        }
    }
}

// --------------- MFMA GEMM: C[M,N] = act(A[M,K] @ W[N,K]^T + b) (+R) ---------------
// BM=128, BK=32, 4 waves 2x2, wave tile 64 x (BN/2), mfma 16x16x32 f16.
// (2-phase structure; retained for the skinny-N shapes: musig N=1024, w2 N=512.)
template <int BN, int ACT, bool RESID, bool SPLIT, typename OutT>
__global__ __launch_bounds__(256) void gemm16_kernel(
    const _Float16* __restrict__ A, const _Float16* __restrict__ Alo,
    const _Float16* __restrict__ W, const _Float16* __restrict__ Wlo,
    const float* __restrict__ bias, const float* __restrict__ bias2,
    const float* __restrict__ R,
    OutT* __restrict__ C, int N, int K, int nsplit) {
    constexpr int BM = 128;
    constexpr int BK = 32;
    constexpr int WN = BN / 2;
    constexpr int MI = 4;            // 64/16
    constexpr int NI = WN / 16;      // 4 (BN=128) or 2 (BN=64)
    constexpr int NS = SPLIT ? 2 : 1;
    constexpr int NBUF = SPLIT ? 2 : 3;
    constexpr int D = NBUF - 1;
    constexpr int LPS = NS * (2 + BN / 64);

    __shared__ alignas(16) _Float16 As[NBUF][NS][BM][BK];
    __shared__ alignas(16) _Float16 Ws[NBUF][NS][BN][BK];

    const int tid  = threadIdx.x;
    const int m0   = blockIdx.x * BM;
    const int n0   = blockIdx.y * BN;

    const int sr = tid >> 2;
    const int sc = tid & 3;
    const int scs = sc ^ ((sr >> 1) & 3);

    const _Float16* Ag[NS];
    const _Float16* Wg[NS];
    Ag[0] = A + (size_t)(m0 + sr) * K + scs * 8;
    Wg[0] = W + (size_t)(n0 + sr) * K + scs * 8;
    if (SPLIT) {
        Ag[1] = Alo + (size_t)(m0 + sr) * K + scs * 8;
        Wg[1] = Wlo + (size_t)(n0 + sr) * K + scs * 8;
    }

    const int wv   = tid >> 6;
    const int wm   = (wv >> 1) * 64;
    const int wn   = (wv & 1) * WN;
    const int lane = tid & 63;
    const int fr   = lane & 15;
    const int q    = lane >> 4;
    const int fk   = (q ^ ((fr >> 1) & 3)) * 8;

    const f32x4 vzero = {0.f, 0.f, 0.f, 0.f};
    f32x4 acc[MI][NI];
    #pragma unroll
    for (int mi = 0; mi < MI; ++mi)
        #pragma unroll
        for (int ni = 0; ni < NI; ++ni) acc[mi][ni] = vzero;

    auto stage = [&](int buf, int k0) {
        #pragma unroll
        for (int s = 0; s < NS; ++s) {
            async16(&As[buf][s][sr][sc * 8], Ag[s] + k0);
            async16(&As[buf][s][64 + sr][sc * 8], Ag[s] + (size_t)64 * K + k0);
            async16(&Ws[buf][s][sr][sc * 8], Wg[s] + k0);
            if (BN == 128)
                async16(&Ws[buf][s][64 + sr][sc * 8], Wg[s] + (size_t)64 * K + k0);
        }
    };

    auto compute = [&](int buf) {
        half8 a[MI], b[NI];
        #pragma unroll
        for (int mi = 0; mi < MI; ++mi)
            a[mi] = *(const half8*)&As[buf][0][wm + mi * 16 + fr][fk];
        #pragma unroll
        for (int ni = 0; ni < NI; ++ni)
            b[ni] = *(const half8*)&Ws[buf][0][wn + ni * 16 + fr][fk];
        #pragma unroll
        for (int mi = 0; mi < MI; ++mi)
            #pragma unroll
            for (int ni = 0; ni < NI; ++ni)
                acc[mi][ni] = __builtin_amdgcn_mfma_f32_16x16x32_f16(
                    a[mi], b[ni], acc[mi][ni], 0, 0, 0);
        if (SPLIT) {
            half8 a2[MI], b2[NI];
            #pragma unroll
            for (int mi = 0; mi < MI; ++mi)
                a2[mi] = *(const half8*)&As[buf][1][wm + mi * 16 + fr][fk];
            #pragma unroll
            for (int ni = 0; ni < NI; ++ni)
                b2[ni] = *(const half8*)&Ws[buf][1][wn + ni * 16 + fr][fk];
            #pragma unroll
            for (int mi = 0; mi < MI; ++mi)
                #pragma unroll
                for (int ni = 0; ni < NI; ++ni)
                    acc[mi][ni] = __builtin_amdgcn_mfma_f32_16x16x32_f16(
                        a2[mi], b[ni], acc[mi][ni], 0, 0, 0);
            #pragma unroll
            for (int mi = 0; mi < MI; ++mi)
                #pragma unroll
                for (int ni = 0; ni < NI; ++ni)
                    acc[mi][ni] = __builtin_amdgcn_mfma_f32_16x16x32_f16(
                        a[mi], b2[ni], acc[mi][ni], 0, 0, 0);
        }
    };

    const int NK = K / BK;

    #pragma unroll
    for (int s = 0; s < D; ++s) stage(s, s * BK);

    int rbuf = 0, sbuf = D;
    for (int ki = 0; ki < NK - D; ++ki) {
        asm volatile("s_waitcnt vmcnt(%0)" :: "n"((D - 1) * LPS) : "memory");
        __builtin_amdgcn_s_barrier();
        stage(sbuf, (ki + D) * BK);
        sbuf = (sbuf + 1 == NBUF) ? 0 : sbuf + 1;
        compute(rbuf);
        rbuf = (rbuf + 1 == NBUF) ? 0 : rbuf + 1;
    }
    if constexpr (D >= 2) {
        asm volatile("s_waitcnt vmcnt(%0)" :: "n"(1 * LPS) : "memory");
        __builtin_amdgcn_s_barrier();
        compute(rbuf);
        rbuf = (rbuf + 1 == NBUF) ? 0 : rbuf + 1;
    }
    asm volatile("s_waitcnt vmcnt(0)" ::: "memory");
    __builtin_amdgcn_s_barrier();
    compute(rbuf);

    const bool fh = (n0 < nsplit);
    const float* bp = fh ? bias : bias2;
    const int coff = fh ? 0 : nsplit;
    const int r0 = (lane >> 4) * 4;
    #pragma unroll
    for (int mi = 0; mi < MI; ++mi) {
        #pragma unroll
        for (int ni = 0; ni < NI; ++ni) {
            const int col = n0 + wn + ni * 16 + fr;
            const float bv = bp[col - coff];
            #pragma unroll
            for (int r = 0; r < 4; ++r) {
                const int row = m0 + wm + mi * 16 + r0 + r;
                float v = acc[mi][ni][r] + bv;
                if (ACT == 1) v = silu_fast(v);
                if (ACT == 2) v = tanhf(v);
                if (ACT == 3 && fh) v = tanhf(v);
                if (RESID) v += R[(size_t)row * N + col];
                C[(size_t)row * N + col] = (OutT)v;
            }
        }
    }
}

// ------- Gaussian kernelized attention update: Q += sum_k S(G,mu,sig)*H -------
// MS is the fused [B,1024] buffer: cols 0..511 = mu, 512..1023 = sig.
__global__ __launch_bounds__(256) void attn_kernel(
    float* __restrict__ Q, const float* __restrict__ MS,
    const float* __restrict__ x,
    const float* __restrict__ omega, const float* __restrict__ G,
    const float* __restrict__ phase) {
    __shared__ float cs[8][260];
    __shared__ float gs[8][260];
    const int tid = threadIdx.x;
    const int b   = blockIdx.x >> 1;
    const int t0  = (blockIdx.x & 1) * 256;
    const float x0 = x[2 * b], x1 = x[2 * b + 1];
    #pragma unroll
    for (int it = 0; it < 8; ++it) {
        int j = it * 256 + tid;            // 0..2047
        int e = t0 * 8 + j;                // flat (t,k) index
        float2 om = *(const float2*)(omega + 2 * e);
        float arg = fmaf(om.x, x0, fmaf(om.y, x1, phase[e]));
        cs[j & 7][j >> 3] = __cosf(arg);
        gs[j & 7][j >> 3] = G[e];
    }
    __syncthreads();
    const int t   = t0 + tid;
    const int idx = blockIdx.x * 256 + tid;   // = b*512 + t
    float mu  = MS[(size_t)b * 1024 + t];
    float sig = MS[(size_t)b * 1024 + 512 + t];
    float inv = -0.5f * __builtin_amdgcn_rcpf(fmaf(sig, sig, EPS_SIG));
    float acc = 0.f;
    #pragma unroll
    for (int k = 0; k < 8; ++k) {
        float d = gs[k][tid] - mu;
        acc = fmaf(__expf(d * d * inv), cs[k][tid], acc);
    }
    Q[idx] += acc;
}

// ---------------- readout: out[b] = silu(Q[b,:]) . ro_w + ro_b ----------------
__global__ __launch_bounds__(256) void readout_kernel(
    const float* __restrict__ Q, const float* __restrict__ row_,
    const float* __restrict__ rob, float* __restrict__ out) {
    int lane = threadIdx.x & 63;
    int row  = blockIdx.x * 4 + (threadIdx.x >> 6);
    const float* qr = Q + (size_t)row * TT;
    float acc = 0.f;
    #pragma unroll
    for (int i = 0; i < 8; ++i) {
        int t = lane * 8 + i;
        acc = fmaf(silu_f(qr[t]), row_[t], acc);
    }
    #pragma unroll
    for (int off = 32; off > 0; off >>= 1) acc += __shfl_down(acc, off);
    if (lane == 0) out[row] = acc + rob[0];
}

} // namespace

extern "C" void kernel_launch(void* const* d_in, const int* in_sizes, int n_in,
                              void* d_out, int out_size, void* d_ws, size_t ws_size,
                              hipStream_t stream) {
    const float* x     = (const float*)d_in[0];
    const float* omega = (const float*)d_in[1];
    const float* G     = (const float*)d_in[2];
    const float* phase = (const float*)d_in[3];
    const float* l1_w  = (const float*)d_in[4];
    const float* l1_b  = (const float*)d_in[5];
    const float* mu_w  = (const float*)d_in[6];
    const float* mu_b  = (const float*)d_in[7];
    const float* sg_w  = (const float*)d_in[8];
    const float* sg_b  = (const float*)d_in[9];
    const float* alqg  = (const float*)d_in[10];
    const float* alqb  = (const float*)d_in[11];
    const float* alfg  = (const float*)d_in[12];
    const float* alfb  = (const float*)d_in[13];
    const float* a_w1  = (const float*)d_in[14];
    const float* a_b1  = (const float*)d_in[15];
    const float* a_w2  = (const float*)d_in[16];
    const float* a_b2  = (const float*)d_in[17];
    const float* mln_g = (const float*)d_in[18];
    const float* mln_b = (const float*)d_in[19];
    const float* m_w1  = (const float*)d_in[20];
    const float* m_b1  = (const float*)d_in[21];
    const float* m_w2  = (const float*)d_in[22];
    const float* m_b2  = (const float*)d_in[23];
    const float* ro_w  = (const float*)d_in[24];
    const float* ro_b  = (const float*)d_in[25];

    // ---- workspace layout (total 100,663,296 B == round-1 proven footprint) ----
    char* ws = (char*)d_ws;
    float*     Q    = (float*)ws;                          // 16 MB  [B,T] fp32
    _Float16*  h_hi = (_Float16*)(ws + 16777216);          //  8 MB  [B,T] f16
    _Float16*  h_lo = (_Float16*)(ws + 25165824);          //  8 MB  [B,T] f16
    _Float16*  mid  = (_Float16*)(ws + 33554432);          // 32 MB  [B,F] f16
    float*     MS   = (float*)(ws + 33554432);             // alias on mid: [B,1024] fp32
    _Float16*  wbuf = (_Float16*)(ws + 67108864);          // 32 MB  f16 weights

    _Float16* msw_hi = wbuf;                     // 4*1024*512 (mu/sig concat)
    _Float16* msw_lo = msw_hi + 2097152;
    _Float16* aw1    = msw_lo + 2097152;         // 4*2048*512
    _Float16* aw2    = aw1 + 4194304;
    _Float16* mw1    = aw2 + 4194304;            // 2*2048*512
    _Float16* mw2    = mw1 + 2097152;

    dim3 blk(256);
    const int BIG = 1 << 30;

    // weight conversion (re-done every call; inputs are re-poisoned by harness)
    cvtcat_kernel<<<1024, blk, 0, stream>>>(mu_w, msw_hi, msw_lo, 0);
    cvtcat_kernel<<<1024, blk, 0, stream>>>(sg_w, msw_hi, msw_lo, 262144);
    cvt_kernel<false><<<4096, blk, 0, stream>>>(a_w1, aw1, nullptr, 4194304);
    cvt_kernel<false><<<4096, blk, 0, stream>>>(a_w2, aw2, nullptr, 4194304);
    cvt_kernel<false><<<2048, blk, 0, stream>>>(m_w1, mw1, nullptr, 2097152);
    cvt_kernel<false><<<2048, blk, 0, stream>>>(m_w2, mw2, nullptr, 2097152);

    tok_kernel<<<BB * TT / 256, blk, 0, stream>>>(x, l1_w, l1_b, Q);

    for (int i = 0; i < 4; ++i) {
        ln_kernel<true><<<BB / 4, blk, 0, stream>>>(
            Q, alqg + i * TT, alqb + i * TT, h_hi, h_lo);
        // fused mu|sig GEMM: N=1024, tanh on mu half only
        gemm16_kernel<64, 3, false, true, float><<<dim3(BB / 128, 1024 / 64), blk, 0, stream>>>(
            h_hi, h_lo, msw_hi + (size_t)i * 524288, msw_lo + (size_t)i * 524288,
            mu_b + i * TT, sg_b + i * TT, nullptr, MS, 1024, TT, TT);
        attn_kernel<<<BB * TT / 256, blk, 0, stream>>>(Q, MS, x, omega, G, phase);
        ln_kernel<false><<<BB / 4, blk, 0, stream>>>(
            Q, alfg + i * TT, alfb + i * TT, h_hi, nullptr);
        gemm256_kernel<<<dim3(BB / 256, FF / 256), dim3(512), 0, stream>>>(
            h_hi, aw1 + (size_t)i * 1048576, a_b1 + i * FF, mid, FF, TT);
        gemm16_kernel<64, 0, true, false, float><<<dim3(BB / 128, TT / 64), blk, 0, stream>>>(
            mid, nullptr, aw2 + (size_t)i * 1048576, nullptr,
            a_b2 + i * TT, a_b2 + i * TT, Q, Q, TT, FF, BIG);
    }
    for (int i = 0; i < 2; ++i) {
        ln_kernel<false><<<BB / 4, blk, 0, stream>>>(
            Q, mln_g + i * TT, mln_b + i * TT, h_hi, nullptr);
        gemm256_kernel<<<dim3(BB / 256, FF / 256), dim3(512), 0, stream>>>(
            h_hi, mw1 + (size_t)i * 1048576, m_b1 + i * FF, mid, FF, TT);
        gemm16_kernel<64, 0, true, false, float><<<dim3(BB / 128, TT / 64), blk, 0, stream>>>(
            mid, nullptr, mw2 + (size_t)i * 1048576, nullptr,
            m_b2 + i * TT, m_b2 + i * TT, Q, Q, TT, FF, BIG);
    }

    readout_kernel<<<BB / 4, blk, 0, stream>>>(Q, ro_w, ro_b, (float*)d_out);
}

// Round 4
// 811.263 us; speedup vs baseline: 1.1734x; 1.0539x over previous
//
#include <hip/hip_runtime.h>
#include <cmath>

namespace {

constexpr int BB = 8192;
constexpr int TT = 512;
constexpr int FF = 2048;
constexpr float EPS_LN  = 1e-5f;
constexpr float EPS_SIG = 1e-8f;

typedef _Float16 half8 __attribute__((ext_vector_type(8)));
typedef _Float16 half4 __attribute__((ext_vector_type(4)));
typedef float f32x4 __attribute__((ext_vector_type(4)));

typedef __attribute__((address_space(1))) void gvoid_t;
typedef __attribute__((address_space(3))) void lvoid_t;

__device__ __forceinline__ void async16(void* lds, const void* g) {
    __builtin_amdgcn_global_load_lds((gvoid_t*)g, (lvoid_t*)lds, 16, 0, 0);
}

__device__ __forceinline__ float silu_f(float v) {
    return v / (1.0f + expf(-v));
}
// fast silu: only for f16-rounded outputs (error ~1e-6 << f16 ulp)
__device__ __forceinline__ float silu_fast(float v) {
    return v * __builtin_amdgcn_rcpf(1.0f + __expf(-v));
}

// ------------- fp32 -> f16 (hi, optional lo residual) weight conversion -------------
template <bool LO>
__global__ __launch_bounds__(256) void cvt_kernel(
    const float* __restrict__ s, _Float16* __restrict__ hi,
    _Float16* __restrict__ lo, int n) {
    int i = (blockIdx.x * 256 + threadIdx.x) * 4;
    if (i >= n) return;
    float4 v = *(const float4*)(s + i);
    half4 h;
    h[0] = (_Float16)v.x; h[1] = (_Float16)v.y;
    h[2] = (_Float16)v.z; h[3] = (_Float16)v.w;
    *(half4*)(hi + i) = h;
    if (LO) {
        half4 l;
        l[0] = (_Float16)(v.x - (float)h[0]);
        l[1] = (_Float16)(v.y - (float)h[1]);
        l[2] = (_Float16)(v.z - (float)h[2]);
        l[3] = (_Float16)(v.w - (float)h[3]);
        *(half4*)(lo + i) = l;
    }
}

// ---- cvt into mu/sig-concatenated layout: src [4][512][512] -> dst [4][1024][512]+base ----
__global__ __launch_bounds__(256) void cvtcat_kernel(
    const float* __restrict__ s, _Float16* __restrict__ hi,
    _Float16* __restrict__ lo, int base) {
    int i = (blockIdx.x * 256 + threadIdx.x) * 4;          // < 4*512*512
    int dst = ((i >> 18) << 19) + base + (i & 262143);
    float4 v = *(const float4*)(s + i);
    half4 h, l;
    h[0] = (_Float16)v.x; h[1] = (_Float16)v.y;
    h[2] = (_Float16)v.z; h[3] = (_Float16)v.w;
    l[0] = (_Float16)(v.x - (float)h[0]);
    l[1] = (_Float16)(v.y - (float)h[1]);
    l[2] = (_Float16)(v.z - (float)h[2]);
    l[3] = (_Float16)(v.w - (float)h[3]);
    *(half4*)(hi + dst) = h;
    *(half4*)(lo + dst) = l;
}

// ---------------- tokenizer: Q[b,t] = silu(x . l1_w[t] + l1_b[t]) ----------------
__global__ __launch_bounds__(256) void tok_kernel(
    const float* __restrict__ x, const float* __restrict__ l1w,
    const float* __restrict__ l1b, float* __restrict__ Q) {
    int idx = blockIdx.x * 256 + threadIdx.x;          // < B*T
    int b = idx >> 9, t = idx & 511;
    float x0 = x[2 * b], x1 = x[2 * b + 1];
    float v = fmaf(x0, l1w[2 * t], fmaf(x1, l1w[2 * t + 1], l1b[t]));
    Q[idx] = silu_f(v);
}

// ------- layernorm (fp32 in, f16 out, optional f16 lo residual), wave per row -------
template <bool LO>
__global__ __launch_bounds__(256) void ln_kernel(
    const float* __restrict__ X, const float* __restrict__ g,
    const float* __restrict__ bia, _Float16* __restrict__ Y,
    _Float16* __restrict__ Ylo) {
    int lane = threadIdx.x & 63;
    int row  = blockIdx.x * 4 + (threadIdx.x >> 6);
    const float* xr = X + (size_t)row * TT;
    float v[8];
    {
        float4 a = *(const float4*)(xr + lane * 8);
        float4 c = *(const float4*)(xr + lane * 8 + 4);
        v[0]=a.x; v[1]=a.y; v[2]=a.z; v[3]=a.w;
        v[4]=c.x; v[5]=c.y; v[6]=c.z; v[7]=c.w;
    }
    float s = 0.f;
    #pragma unroll
    for (int i = 0; i < 8; ++i) s += v[i];
    #pragma unroll
    for (int off = 32; off > 0; off >>= 1) s += __shfl_down(s, off);
    float mean = __shfl(s, 0) * (1.0f / TT);
    float ss = 0.f;
    #pragma unroll
    for (int i = 0; i < 8; ++i) { float d = v[i] - mean; ss = fmaf(d, d, ss); }
    #pragma unroll
    for (int off = 32; off > 0; off >>= 1) ss += __shfl_down(ss, off);
    float var  = __shfl(ss, 0) * (1.0f / TT);
    float rstd = rsqrtf(var + EPS_LN);
    half8 hv, lv;
    #pragma unroll
    for (int i = 0; i < 8; ++i) {
        int t = lane * 8 + i;
        float o = (v[i] - mean) * rstd * g[t] + bia[t];
        hv[i] = (_Float16)o;
        if (LO) lv[i] = (_Float16)(o - (float)hv[i]);
    }
    *(half8*)(Y + (size_t)row * TT + lane * 8) = hv;
    if (LO) *(half8*)(Ylo + (size_t)row * TT + lane * 8) = lv;
}

// ========== unified deep-pipelined MFMA GEMM (T3+T4+T5): C = act(A@W^T + b) (+R) =====
// Tile BM x BN, WGM x WGN waves (wave tile (BM/WGM) x (BN/WGN)), BK=32, mfma 16x16x32.
// LDS ring of NBUF K-tile buffers; D=NBUF-1 tiles in flight; steady-state counted
// s_waitcnt vmcnt((D-1)*LPT) -- NEVER drained in the main loop; ONE raw s_barrier
// per K-iter; setprio(1) around the MFMA cluster (proven R3 on the w1 shape).
// Hazards: stage(t+D) targets buf (t+D)%NBUF == ring slot last read at iter t-1,
// consumed before every wave passed barrier t. Read of tile t: own loads retired by
// the counted vmcnt (oldest LPT of D*LPT), other waves' published by the barrier.
// Source-side XOR chunk swizzle: 16B chunk c of row r staged from source chunk
// c^((r>>1)&3) -> fragment ds_read_b128 at col (q^((fr>>1)&3))*8 is conflict-free
// (measured 0 bank conflicts across R0-R3).
// SPLIT: acc = A@W + Alo@W + A@Wlo (near-fp32 from f16 inputs).
// ACT: 0=none, 1=silu_fast, 3=tanh for cols<nsplit else none (fused mu|sig).
// bias: cols<nsplit from bias[], else bias2[col-nsplit] (block-uniform select).
template <int BM, int BN, int WGM, int WGN, int NBUF, bool SPLIT, int ACT,
          bool RESID, typename OutT>
__global__ __launch_bounds__(WGM * WGN * 64) void gemmdp_kernel(
    const _Float16* __restrict__ A, const _Float16* __restrict__ Alo,
    const _Float16* __restrict__ W, const _Float16* __restrict__ Wlo,
    const float* __restrict__ bias, const float* __restrict__ bias2,
    const float* __restrict__ R, OutT* __restrict__ C,
    int N, int K, int nsplit) {
    constexpr int BK      = 32;                    // halves per K-tile
    constexpr int THREADS = WGM * WGN * 64;
    constexpr int NS   = SPLIT ? 2 : 1;
    constexpr int D    = NBUF - 1;
    constexpr int CH_A = NS * BM * 4;              // 16B chunks of A per tile
    constexpr int CH_T = NS * (BM + BN) * 4;
    constexpr int LPT  = CH_T / THREADS;           // loads/thread/tile
    static_assert(CH_T % THREADS == 0 && CH_A % THREADS == 0, "staging split");
    constexpr int ABUF = NS * BM * BK;             // halves per buf (A region)
    constexpr int WBUF = NS * BN * BK;
    constexpr int WOFF = NBUF * ABUF;              // W region base
    constexpr int WTM  = BM / WGM;
    constexpr int WTN  = BN / WGN;
    constexpr int MI   = WTM / 16;
    constexpr int NI   = WTN / 16;

    __shared__ alignas(16) _Float16 lds[NBUF * (ABUF + WBUF)];

    const int tid = threadIdx.x;
    const int m0  = blockIdx.x * BM;
    const int n0  = blockIdx.y * BN;

    const _Float16* Asrc[2] = {A, Alo};
    const _Float16* Wsrc[2] = {W, Wlo};

    // ---- staging plan (fully unrolled -> registers; per-j branch is uniform) ----
    const _Float16* gsrc[LPT];
    int off0[LPT], bstr[LPT];
    #pragma unroll
    for (int j = 0; j < LPT; ++j) {
        int idx = j * THREADS + tid;
        if (j * THREADS < CH_A) {                  // A chunk (compile-time per j)
            int s   = idx / (BM * 4);
            int rc  = idx % (BM * 4);
            int row = rc >> 2, sl = rc & 3;
            int src = sl ^ ((row >> 1) & 3);
            gsrc[j] = Asrc[s] + (size_t)(m0 + row) * K + src * 8;
            off0[j] = (s * BM + row) * BK + sl * 8;
            bstr[j] = ABUF;
        } else {                                   // W chunk
            int i2  = idx - CH_A;
            int s   = i2 / (BN * 4);
            int rc  = i2 % (BN * 4);
            int row = rc >> 2, sl = rc & 3;
            int src = sl ^ ((row >> 1) & 3);
            gsrc[j] = Wsrc[s] + (size_t)(n0 + row) * K + src * 8;
            off0[j] = WOFF + (s * BN + row) * BK + sl * 8;
            bstr[j] = WBUF;
        }
    }

    auto stage = [&](int buf, int k0) {
        #pragma unroll
        for (int j = 0; j < LPT; ++j)
            async16(&lds[off0[j] + buf * bstr[j]], gsrc[j] + k0);
    };

    // ---- fragment geometry ----
    const int wid  = tid >> 6;
    const int wr   = wid / WGN;
    const int wc   = wid % WGN;
    const int lane = tid & 63;
    const int fr   = lane & 15;
    const int q    = lane >> 4;
    const int swz  = (q ^ ((fr >> 1) & 3)) * 8;    // swizzled k-offset (halves)

    const f32x4 vzero = {0.f, 0.f, 0.f, 0.f};
    f32x4 acc[MI][NI];
    #pragma unroll
    for (int mi = 0; mi < MI; ++mi)
        #pragma unroll
        for (int ni = 0; ni < NI; ++ni) acc[mi][ni] = vzero;

    auto body = [&](int buf) {
        const int da = buf * ABUF;
        const int dw = WOFF + buf * WBUF;
        half8 a[NS][MI], b[NS][NI];
        #pragma unroll
        for (int s = 0; s < NS; ++s) {
            #pragma unroll
            for (int mi = 0; mi < MI; ++mi)
                a[s][mi] = *(const half8*)&lds[da + (s * BM + wr * WTM + mi * 16 + fr) * BK + swz];
            #pragma unroll
            for (int ni = 0; ni < NI; ++ni)
                b[s][ni] = *(const half8*)&lds[dw + (s * BN + wc * WTN + ni * 16 + fr) * BK + swz];
        }
        __builtin_amdgcn_s_setprio(1);
        #pragma unroll
        for (int mi = 0; mi < MI; ++mi)
            #pragma unroll
            for (int ni = 0; ni < NI; ++ni)
                acc[mi][ni] = __builtin_amdgcn_mfma_f32_16x16x32_f16(
                    a[0][mi], b[0][ni], acc[mi][ni], 0, 0, 0);
        if (SPLIT) {
            #pragma unroll
            for (int mi = 0; mi < MI; ++mi)
                #pragma unroll
                for (int ni = 0; ni < NI; ++ni)
                    acc[mi][ni] = __builtin_amdgcn_mfma_f32_16x16x32_f16(
                        a[1][mi], b[0][ni], acc[mi][ni], 0, 0, 0);
            #pragma unroll
            for (int mi = 0; mi < MI; ++mi)
                #pragma unroll
                for (int ni = 0; ni < NI; ++ni)
                    acc[mi][ni] = __builtin_amdgcn_mfma_f32_16x16x32_f16(
                        a[0][mi], b[1][ni], acc[mi][ni], 0, 0, 0);
        }
        __builtin_amdgcn_s_setprio(0);
    };

    const int NK = K / BK;                          // 16 (K=512) or 64 (K=2048)

    #pragma unroll
    for (int s = 0; s < D; ++s) stage(s, s * BK);

    int rbuf = 0, sbuf = D;
    for (int ki = 0; ki < NK - D; ++ki) {
        asm volatile("s_waitcnt vmcnt(%0)" :: "n"((D - 1) * LPT) : "memory");
        __builtin_amdgcn_s_barrier();
        asm volatile("" ::: "memory");
        stage(sbuf, (ki + D) * BK);
        sbuf = (sbuf + 1 == NBUF) ? 0 : sbuf + 1;
        body(rbuf);
        rbuf = (rbuf + 1 == NBUF) ? 0 : rbuf + 1;
    }
    if constexpr (D >= 3) {
        asm volatile("s_waitcnt vmcnt(%0)" :: "n"(2 * LPT) : "memory");
        __builtin_amdgcn_s_barrier();
        asm volatile("" ::: "memory");
        body(rbuf);
        rbuf = (rbuf + 1 == NBUF) ? 0 : rbuf + 1;
    }
    if constexpr (D >= 2) {
        asm volatile("s_waitcnt vmcnt(%0)" :: "n"(1 * LPT) : "memory");
        __builtin_amdgcn_s_barrier();
        asm volatile("" ::: "memory");
        body(rbuf);
        rbuf = (rbuf + 1 == NBUF) ? 0 : rbuf + 1;
    }
    asm volatile("s_waitcnt vmcnt(0)" ::: "memory");
    __builtin_amdgcn_s_barrier();
    asm volatile("" ::: "memory");
    body(rbuf);

    // ---- epilogue; C/D layout: col = lane&15, row = (lane>>4)*4 + reg ----
    const bool fh = (n0 < nsplit);                  // block-uniform half select
    const float* bp = fh ? bias : bias2;
    const int coff = fh ? 0 : nsplit;
    const int r0 = q * 4;
    #pragma unroll
    for (int mi = 0; mi < MI; ++mi) {
        #pragma unroll
        for (int ni = 0; ni < NI; ++ni) {
            const int col = n0 + wc * WTN + ni * 16 + fr;
            const float bv = bp[col - coff];
            #pragma unroll
            for (int r = 0; r < 4; ++r) {
                const int row = m0 + wr * WTM + mi * 16 + r0 + r;
                float v = acc[mi][ni][r] + bv;
                if (ACT == 1) v = silu_fast(v);
                if (ACT == 3 && fh) v = tanhf(v);
                if (RESID) v += R[(size_t)row * N + col];
                C[(size_t)row * N + col] = (OutT)v;
            }
        }
    }
}

// ------- Gaussian kernelized attention update: Q += sum_k S(G,mu,sig)*H -------
// MS is the fused [B,1024] buffer: cols 0..511 = mu, 512..1023 = sig.
__global__ __launch_bounds__(256) void attn_kernel(
    float* __restrict__ Q, const float* __restrict__ MS,
    const float* __restrict__ x,
    const float* __restrict__ omega, const float* __restrict__ G,
    const float* __restrict__ phase) {
    __shared__ float cs[8][260];
    __shared__ float gs[8][260];
    const int tid = threadIdx.x;
    const int b   = blockIdx.x >> 1;
    const int t0  = (blockIdx.x & 1) * 256;
    const float x0 = x[2 * b], x1 = x[2 * b + 1];
    #pragma unroll
    for (int it = 0; it < 8; ++it) {
        int j = it * 256 + tid;            // 0..2047
        int e = t0 * 8 + j;                // flat (t,k) index
        float2 om = *(const float2*)(omega + 2 * e);
        float arg = fmaf(om.x, x0, fmaf(om.y, x1, phase[e]));
        cs[j & 7][j >> 3] = __cosf(arg);
        gs[j & 7][j >> 3] = G[e];
    }
    __syncthreads();
    const int t   = t0 + tid;
    const int idx = blockIdx.x * 256 + tid;   // = b*512 + t
    float mu  = MS[(size_t)b * 1024 + t];
    float sig = MS[(size_t)b * 1024 + 512 + t];
    float inv = -0.5f * __builtin_amdgcn_rcpf(fmaf(sig, sig, EPS_SIG));
    float acc = 0.f;
    #pragma unroll
    for (int k = 0; k < 8; ++k) {
        float d = gs[k][tid] - mu;
        acc = fmaf(__expf(d * d * inv), cs[k][tid], acc);
    }
    Q[idx] += acc;
}

// ---------------- readout: out[b] = silu(Q[b,:]) . ro_w + ro_b ----------------
__global__ __launch_bounds__(256) void readout_kernel(
    const float* __restrict__ Q, const float* __restrict__ row_,
    const float* __restrict__ rob, float* __restrict__ out) {
    int lane = threadIdx.x & 63;
    int row  = blockIdx.x * 4 + (threadIdx.x >> 6);
    const float* qr = Q + (size_t)row * TT;
    float acc = 0.f;
    #pragma unroll
    for (int i = 0; i < 8; ++i) {
        int t = lane * 8 + i;
        acc = fmaf(silu_f(qr[t]), row_[t], acc);
    }
    #pragma unroll
    for (int off = 32; off > 0; off >>= 1) acc += __shfl_down(acc, off);
    if (lane == 0) out[row] = acc + rob[0];
}

} // namespace

extern "C" void kernel_launch(void* const* d_in, const int* in_sizes, int n_in,
                              void* d_out, int out_size, void* d_ws, size_t ws_size,
                              hipStream_t stream) {
    const float* x     = (const float*)d_in[0];
    const float* omega = (const float*)d_in[1];
    const float* G     = (const float*)d_in[2];
    const float* phase = (const float*)d_in[3];
    const float* l1_w  = (const float*)d_in[4];
    const float* l1_b  = (const float*)d_in[5];
    const float* mu_w  = (const float*)d_in[6];
    const float* mu_b  = (const float*)d_in[7];
    const float* sg_w  = (const float*)d_in[8];
    const float* sg_b  = (const float*)d_in[9];
    const float* alqg  = (const float*)d_in[10];
    const float* alqb  = (const float*)d_in[11];
    const float* alfg  = (const float*)d_in[12];
    const float* alfb  = (const float*)d_in[13];
    const float* a_w1  = (const float*)d_in[14];
    const float* a_b1  = (const float*)d_in[15];
    const float* a_w2  = (const float*)d_in[16];
    const float* a_b2  = (const float*)d_in[17];
    const float* mln_g = (const float*)d_in[18];
    const float* mln_b = (const float*)d_in[19];
    const float* m_w1  = (const float*)d_in[20];
    const float* m_b1  = (const float*)d_in[21];
    const float* m_w2  = (const float*)d_in[22];
    const float* m_b2  = (const float*)d_in[23];
    const float* ro_w  = (const float*)d_in[24];
    const float* ro_b  = (const float*)d_in[25];

    // ---- workspace layout (total 100,663,296 B == round-1 proven footprint) ----
    char* ws = (char*)d_ws;
    float*     Q    = (float*)ws;                          // 16 MB  [B,T] fp32
    _Float16*  h_hi = (_Float16*)(ws + 16777216);          //  8 MB  [B,T] f16
    _Float16*  h_lo = (_Float16*)(ws + 25165824);          //  8 MB  [B,T] f16
    _Float16*  mid  = (_Float16*)(ws + 33554432);          // 32 MB  [B,F] f16
    float*     MS   = (float*)(ws + 33554432);             // alias on mid: [B,1024] fp32
    _Float16*  wbuf = (_Float16*)(ws + 67108864);          // 32 MB  f16 weights

    _Float16* msw_hi = wbuf;                     // 4*1024*512 (mu/sig concat)
    _Float16* msw_lo = msw_hi + 2097152;
    _Float16* aw1    = msw_lo + 2097152;         // 4*2048*512
    _Float16* aw2    = aw1 + 4194304;
    _Float16* mw1    = aw2 + 4194304;            // 2*2048*512
    _Float16* mw2    = mw1 + 2097152;

    dim3 blk(256);
    const int BIG = 1 << 30;

    // weight conversion (re-done every call; inputs are re-poisoned by harness)
    cvtcat_kernel<<<1024, blk, 0, stream>>>(mu_w, msw_hi, msw_lo, 0);
    cvtcat_kernel<<<1024, blk, 0, stream>>>(sg_w, msw_hi, msw_lo, 262144);
    cvt_kernel<false><<<4096, blk, 0, stream>>>(a_w1, aw1, nullptr, 4194304);
    cvt_kernel<false><<<4096, blk, 0, stream>>>(a_w2, aw2, nullptr, 4194304);
    cvt_kernel<false><<<2048, blk, 0, stream>>>(m_w1, mw1, nullptr, 2097152);
    cvt_kernel<false><<<2048, blk, 0, stream>>>(m_w2, mw2, nullptr, 2097152);

    tok_kernel<<<BB * TT / 256, blk, 0, stream>>>(x, l1_w, l1_b, Q);

    for (int i = 0; i < 4; ++i) {
        ln_kernel<true><<<BB / 4, blk, 0, stream>>>(
            Q, alqg + i * TT, alqb + i * TT, h_hi, h_lo);
        // fused mu|sig SPLIT GEMM: N=1024, deep pipeline, tanh on mu half only
        gemmdp_kernel<256, 128, 2, 4, 3, true, 3, false, float>
            <<<dim3(BB / 256, 1024 / 128), dim3(512), 0, stream>>>(
            h_hi, h_lo, msw_hi + (size_t)i * 524288, msw_lo + (size_t)i * 524288,
            mu_b + i * TT, sg_b + i * TT, nullptr, MS, 1024, TT, TT);
        attn_kernel<<<BB * TT / 256, blk, 0, stream>>>(Q, MS, x, omega, G, phase);
        ln_kernel<false><<<BB / 4, blk, 0, stream>>>(
            Q, alfg + i * TT, alfb + i * TT, h_hi, nullptr);
        gemmdp_kernel<256, 256, 2, 4, 4, false, 1, false, _Float16>
            <<<dim3(BB / 256, FF / 256), dim3(512), 0, stream>>>(
            h_hi, nullptr, aw1 + (size_t)i * 1048576, nullptr,
            a_b1 + i * FF, a_b1 + i * FF, nullptr, mid, FF, TT, BIG);
        gemmdp_kernel<128, 128, 2, 2, 4, false, 0, true, float>
            <<<dim3(BB / 128, TT / 128), dim3(256), 0, stream>>>(
            mid, nullptr, aw2 + (size_t)i * 1048576, nullptr,
            a_b2 + i * TT, a_b2 + i * TT, Q, Q, TT, FF, BIG);
    }
    for (int i = 0; i < 2; ++i) {
        ln_kernel<false><<<BB / 4, blk, 0, stream>>>(
            Q, mln_g + i * TT, mln_b + i * TT, h_hi, nullptr);
        gemmdp_kernel<256, 256, 2, 4, 4, false, 1, false, _Float16>
            <<<dim3(BB / 256, FF / 256), dim3(512), 0, stream>>>(
            h_hi, nullptr, mw1 + (size_t)i * 1048576, nullptr,
            m_b1 + i * FF, m_b1 + i * FF, nullptr, mid, FF, TT, BIG);
        gemmdp_kernel<128, 128, 2, 2, 4, false, 0, true, float>
            <<<dim3(BB / 128, TT / 128), dim3(256), 0, stream>>>(
            mid, nullptr, mw2 + (size_t)i * 1048576, nullptr,
            m_b2 + i * TT, m_b2 + i * TT, Q, Q, TT, FF, BIG);
    }

    readout_kernel<<<BB / 4, blk, 0, stream>>>(Q, ro_w, ro_b, (float*)d_out);
}

// Round 5
// 784.800 us; speedup vs baseline: 1.2130x; 1.0337x over previous
//
#include <hip/hip_runtime.h>
#include <cmath>

namespace {

constexpr int BB = 8192;
constexpr int TT = 512;
constexpr int FF = 2048;
constexpr float EPS_LN  = 1e-5f;
constexpr float EPS_SIG = 1e-8f;

typedef _Float16 half8 __attribute__((ext_vector_type(8)));
typedef _Float16 half4 __attribute__((ext_vector_type(4)));
typedef float f32x4 __attribute__((ext_vector_type(4)));

typedef __attribute__((address_space(1))) void gvoid_t;
typedef __attribute__((address_space(3))) void lvoid_t;

__device__ __forceinline__ void async16(void* lds, const void* g) {
    __builtin_amdgcn_global_load_lds((gvoid_t*)g, (lvoid_t*)lds, 16, 0, 0);
}

__device__ __forceinline__ float silu_f(float v) {
    return v / (1.0f + expf(-v));
}
// fast silu: only for f16-rounded outputs (error ~1e-6 << f16 ulp)
__device__ __forceinline__ float silu_fast(float v) {
    return v * __builtin_amdgcn_rcpf(1.0f + __expf(-v));
}

// ------------- fp32 -> f16 (hi, optional lo residual) weight conversion -------------
template <bool LO>
__global__ __launch_bounds__(256) void cvt_kernel(
    const float* __restrict__ s, _Float16* __restrict__ hi,
    _Float16* __restrict__ lo, int n) {
    int i = (blockIdx.x * 256 + threadIdx.x) * 4;
    if (i >= n) return;
    float4 v = *(const float4*)(s + i);
    half4 h;
    h[0] = (_Float16)v.x; h[1] = (_Float16)v.y;
    h[2] = (_Float16)v.z; h[3] = (_Float16)v.w;
    *(half4*)(hi + i) = h;
    if (LO) {
        half4 l;
        l[0] = (_Float16)(v.x - (float)h[0]);
        l[1] = (_Float16)(v.y - (float)h[1]);
        l[2] = (_Float16)(v.z - (float)h[2]);
        l[3] = (_Float16)(v.w - (float)h[3]);
        *(half4*)(lo + i) = l;
    }
}

// ---- cvt into mu/sig-concatenated layout: src [4][512][512] -> dst [4][1024][512]+base ----
__global__ __launch_bounds__(256) void cvtcat_kernel(
    const float* __restrict__ s, _Float16* __restrict__ hi,
    _Float16* __restrict__ lo, int base) {
    int i = (blockIdx.x * 256 + threadIdx.x) * 4;          // < 4*512*512
    int dst = ((i >> 18) << 19) + base + (i & 262143);
    float4 v = *(const float4*)(s + i);
    half4 h, l;
    h[0] = (_Float16)v.x; h[1] = (_Float16)v.y;
    h[2] = (_Float16)v.z; h[3] = (_Float16)v.w;
    l[0] = (_Float16)(v.x - (float)h[0]);
    l[1] = (_Float16)(v.y - (float)h[1]);
    l[2] = (_Float16)(v.z - (float)h[2]);
    l[3] = (_Float16)(v.w - (float)h[3]);
    *(half4*)(hi + dst) = h;
    *(half4*)(lo + dst) = l;
}

// ---------------- tokenizer: Q[b,t] = silu(x . l1_w[t] + l1_b[t]) ----------------
__global__ __launch_bounds__(256) void tok_kernel(
    const float* __restrict__ x, const float* __restrict__ l1w,
    const float* __restrict__ l1b, float* __restrict__ Q) {
    int idx = blockIdx.x * 256 + threadIdx.x;          // < B*T
    int b = idx >> 9, t = idx & 511;
    float x0 = x[2 * b], x1 = x[2 * b + 1];
    float v = fmaf(x0, l1w[2 * t], fmaf(x1, l1w[2 * t + 1], l1b[t]));
    Q[idx] = silu_f(v);
}

// ------- layernorm (fp32 in, f16 out, optional f16 lo residual), wave per row -------
template <bool LO>
__global__ __launch_bounds__(256) void ln_kernel(
    const float* __restrict__ X, const float* __restrict__ g,
    const float* __restrict__ bia, _Float16* __restrict__ Y,
    _Float16* __restrict__ Ylo) {
    int lane = threadIdx.x & 63;
    int row  = blockIdx.x * 4 + (threadIdx.x >> 6);
    const float* xr = X + (size_t)row * TT;
    float v[8];
    {
        float4 a = *(const float4*)(xr + lane * 8);
        float4 c = *(const float4*)(xr + lane * 8 + 4);
        v[0]=a.x; v[1]=a.y; v[2]=a.z; v[3]=a.w;
        v[4]=c.x; v[5]=c.y; v[6]=c.z; v[7]=c.w;
    }
    float s = 0.f;
    #pragma unroll
    for (int i = 0; i < 8; ++i) s += v[i];
    #pragma unroll
    for (int off = 32; off > 0; off >>= 1) s += __shfl_down(s, off);
    float mean = __shfl(s, 0) * (1.0f / TT);
    float ss = 0.f;
    #pragma unroll
    for (int i = 0; i < 8; ++i) { float d = v[i] - mean; ss = fmaf(d, d, ss); }
    #pragma unroll
    for (int off = 32; off > 0; off >>= 1) ss += __shfl_down(ss, off);
    float var  = __shfl(ss, 0) * (1.0f / TT);
    float rstd = rsqrtf(var + EPS_LN);
    half8 hv, lv;
    #pragma unroll
    for (int i = 0; i < 8; ++i) {
        int t = lane * 8 + i;
        float o = (v[i] - mean) * rstd * g[t] + bia[t];
        hv[i] = (_Float16)o;
        if (LO) lv[i] = (_Float16)(o - (float)hv[i]);
    }
    *(half8*)(Y + (size_t)row * TT + lane * 8) = hv;
    if (LO) *(half8*)(Ylo + (size_t)row * TT + lane * 8) = lv;
}

// ========== unified deep-pipelined MFMA GEMM (T3+T4+T5): C = act(A@W^T + b) (+R) =====
// Tile BM x BN, WGM x WGN waves (wave tile (BM/WGM) x (BN/WGN)), BK=32, mfma 16x16x32.
// LDS ring of NBUF K-tile buffers; D=NBUF-1 tiles in flight; steady-state counted
// s_waitcnt vmcnt((D-1)*LPT) -- NEVER drained in the main loop; ONE raw s_barrier
// per K-iter; setprio(1) around the MFMA cluster. >= 8 waves (2/SIMD) so one wave's
// MFMA cluster hides the other's ds_read/stage (the R3-proven mechanism).
// Source-side XOR chunk swizzle -> conflict-free ds_read_b128 (0 conflicts R0-R4).
// SPLIT: acc = A@W + Alo@W + A@Wlo (near-fp32 from f16 inputs).
// ACT: 0=none, 1=silu_fast, 3=tanh for cols<nsplit else none (fused mu|sig).
// bias: cols<nsplit from bias[], else bias2[col-nsplit] (block-uniform select).
template <int BM, int BN, int WGM, int WGN, int NBUF, bool SPLIT, int ACT,
          bool RESID, typename OutT>
__global__ __launch_bounds__(WGM * WGN * 64) void gemmdp_kernel(
    const _Float16* __restrict__ A, const _Float16* __restrict__ Alo,
    const _Float16* __restrict__ W, const _Float16* __restrict__ Wlo,
    const float* __restrict__ bias, const float* __restrict__ bias2,
    const float* __restrict__ R, OutT* __restrict__ C,
    int N, int K, int nsplit) {
    constexpr int BK      = 32;                    // halves per K-tile
    constexpr int THREADS = WGM * WGN * 64;
    constexpr int NS   = SPLIT ? 2 : 1;
    constexpr int D    = NBUF - 1;
    constexpr int CH_A = NS * BM * 4;              // 16B chunks of A per tile
    constexpr int CH_T = NS * (BM + BN) * 4;
    constexpr int LPT  = CH_T / THREADS;           // loads/thread/tile
    static_assert(CH_T % THREADS == 0 && CH_A % THREADS == 0, "staging split");
    constexpr int ABUF = NS * BM * BK;             // halves per buf (A region)
    constexpr int WBUF = NS * BN * BK;
    constexpr int WOFF = NBUF * ABUF;              // W region base
    constexpr int WTM  = BM / WGM;
    constexpr int WTN  = BN / WGN;
    constexpr int MI   = WTM / 16;
    constexpr int NI   = WTN / 16;

    __shared__ alignas(16) _Float16 lds[NBUF * (ABUF + WBUF)];

    const int tid = threadIdx.x;
    const int m0  = blockIdx.x * BM;
    const int n0  = blockIdx.y * BN;

    const _Float16* Asrc[2] = {A, Alo};
    const _Float16* Wsrc[2] = {W, Wlo};

    // ---- staging plan (fully unrolled -> registers; per-j branch is uniform) ----
    const _Float16* gsrc[LPT];
    int off0[LPT], bstr[LPT];
    #pragma unroll
    for (int j = 0; j < LPT; ++j) {
        int idx = j * THREADS + tid;
        if (j * THREADS < CH_A) {                  // A chunk (compile-time per j)
            int s   = idx / (BM * 4);
            int rc  = idx % (BM * 4);
            int row = rc >> 2, sl = rc & 3;
            int src = sl ^ ((row >> 1) & 3);
            gsrc[j] = Asrc[s] + (size_t)(m0 + row) * K + src * 8;
            off0[j] = (s * BM + row) * BK + sl * 8;
            bstr[j] = ABUF;
        } else {                                   // W chunk
            int i2  = idx - CH_A;
            int s   = i2 / (BN * 4);
            int rc  = i2 % (BN * 4);
            int row = rc >> 2, sl = rc & 3;
            int src = sl ^ ((row >> 1) & 3);
            gsrc[j] = Wsrc[s] + (size_t)(n0 + row) * K + src * 8;
            off0[j] = WOFF + (s * BN + row) * BK + sl * 8;
            bstr[j] = WBUF;
        }
    }

    auto stage = [&](int buf, int k0) {
        #pragma unroll
        for (int j = 0; j < LPT; ++j)
            async16(&lds[off0[j] + buf * bstr[j]], gsrc[j] + k0);
    };

    // ---- fragment geometry ----
    const int wid  = tid >> 6;
    const int wr   = wid / WGN;
    const int wc   = wid % WGN;
    const int lane = tid & 63;
    const int fr   = lane & 15;
    const int q    = lane >> 4;
    const int swz  = (q ^ ((fr >> 1) & 3)) * 8;    // swizzled k-offset (halves)

    const f32x4 vzero = {0.f, 0.f, 0.f, 0.f};
    f32x4 acc[MI][NI];
    #pragma unroll
    for (int mi = 0; mi < MI; ++mi)
        #pragma unroll
        for (int ni = 0; ni < NI; ++ni) acc[mi][ni] = vzero;

    auto body = [&](int buf) {
        const int da = buf * ABUF;
        const int dw = WOFF + buf * WBUF;
        half8 a[NS][MI], b[NS][NI];
        #pragma unroll
        for (int s = 0; s < NS; ++s) {
            #pragma unroll
            for (int mi = 0; mi < MI; ++mi)
                a[s][mi] = *(const half8*)&lds[da + (s * BM + wr * WTM + mi * 16 + fr) * BK + swz];
            #pragma unroll
            for (int ni = 0; ni < NI; ++ni)
                b[s][ni] = *(const half8*)&lds[dw + (s * BN + wc * WTN + ni * 16 + fr) * BK + swz];
        }
        __builtin_amdgcn_s_setprio(1);
        #pragma unroll
        for (int mi = 0; mi < MI; ++mi)
            #pragma unroll
            for (int ni = 0; ni < NI; ++ni)
                acc[mi][ni] = __builtin_amdgcn_mfma_f32_16x16x32_f16(
                    a[0][mi], b[0][ni], acc[mi][ni], 0, 0, 0);
        if (SPLIT) {
            #pragma unroll
            for (int mi = 0; mi < MI; ++mi)
                #pragma unroll
                for (int ni = 0; ni < NI; ++ni)
                    acc[mi][ni] = __builtin_amdgcn_mfma_f32_16x16x32_f16(
                        a[1][mi], b[0][ni], acc[mi][ni], 0, 0, 0);
            #pragma unroll
            for (int mi = 0; mi < MI; ++mi)
                #pragma unroll
                for (int ni = 0; ni < NI; ++ni)
                    acc[mi][ni] = __builtin_amdgcn_mfma_f32_16x16x32_f16(
                        a[0][mi], b[1][ni], acc[mi][ni], 0, 0, 0);
        }
        __builtin_amdgcn_s_setprio(0);
    };

    const int NK = K / BK;                          // 16 (K=512) or 64 (K=2048)

    #pragma unroll
    for (int s = 0; s < D; ++s) stage(s, s * BK);

    int rbuf = 0, sbuf = D;
    for (int ki = 0; ki < NK - D; ++ki) {
        asm volatile("s_waitcnt vmcnt(%0)" :: "n"((D - 1) * LPT) : "memory");
        __builtin_amdgcn_s_barrier();
        asm volatile("" ::: "memory");
        stage(sbuf, (ki + D) * BK);
        sbuf = (sbuf + 1 == NBUF) ? 0 : sbuf + 1;
        body(rbuf);
        rbuf = (rbuf + 1 == NBUF) ? 0 : rbuf + 1;
    }
    if constexpr (D >= 3) {
        asm volatile("s_waitcnt vmcnt(%0)" :: "n"(2 * LPT) : "memory");
        __builtin_amdgcn_s_barrier();
        asm volatile("" ::: "memory");
        body(rbuf);
        rbuf = (rbuf + 1 == NBUF) ? 0 : rbuf + 1;
    }
    if constexpr (D >= 2) {
        asm volatile("s_waitcnt vmcnt(%0)" :: "n"(1 * LPT) : "memory");
        __builtin_amdgcn_s_barrier();
        asm volatile("" ::: "memory");
        body(rbuf);
        rbuf = (rbuf + 1 == NBUF) ? 0 : rbuf + 1;
    }
    asm volatile("s_waitcnt vmcnt(0)" ::: "memory");
    __builtin_amdgcn_s_barrier();
    asm volatile("" ::: "memory");
    body(rbuf);

    // ---- epilogue; C/D layout: col = lane&15, row = (lane>>4)*4 + reg ----
    const bool fh = (n0 < nsplit);                  // block-uniform half select
    const float* bp = fh ? bias : bias2;
    const int coff = fh ? 0 : nsplit;
    const int r0 = q * 4;
    #pragma unroll
    for (int mi = 0; mi < MI; ++mi) {
        #pragma unroll
        for (int ni = 0; ni < NI; ++ni) {
            const int col = n0 + wc * WTN + ni * 16 + fr;
            const float bv = bp[col - coff];
            #pragma unroll
            for (int r = 0; r < 4; ++r) {
                const int row = m0 + wr * WTM + mi * 16 + r0 + r;
                float v = acc[mi][ni][r] + bv;
                if (ACT == 1) v = silu_fast(v);
                if (ACT == 3 && fh) v = tanhf(v);
                if (RESID) v += R[(size_t)row * N + col];
                C[(size_t)row * N + col] = (OutT)v;
            }
        }
    }
}

// ==== fused attention update + layernorm: Q += sum_k S*H; h = LN(Q)*g+b -> f16 ====
// One block per batch row b, 512 threads = one token each. MS is the fused [B,1024]
// mu|sig buffer. After the update, block-wide two-pass LN (wave shuffle + 8-slot
// LDS cross-wave reduce) emits h_hi directly -- saves the separate ln dispatch and
// its 16MB Q re-read.
__global__ __launch_bounds__(512) void attnln_kernel(
    float* __restrict__ Q, const float* __restrict__ MS,
    const float* __restrict__ x,
    const float* __restrict__ omega, const float* __restrict__ G,
    const float* __restrict__ phase,
    const float* __restrict__ g, const float* __restrict__ bia,
    _Float16* __restrict__ Y) {
    __shared__ float cs[8][516];
    __shared__ float gs[8][516];
    __shared__ float red[2][8];
    const int tid = threadIdx.x;
    const int b   = blockIdx.x;
    const float x0 = x[2 * b], x1 = x[2 * b + 1];
    #pragma unroll
    for (int it = 0; it < 8; ++it) {
        int j = it * 512 + tid;            // 0..4095 flat (t,k) index
        float2 om = *(const float2*)(omega + 2 * j);
        float arg = fmaf(om.x, x0, fmaf(om.y, x1, phase[j]));
        cs[j & 7][j >> 3] = __cosf(arg);
        gs[j & 7][j >> 3] = G[j];
    }
    __syncthreads();
    const int t = tid;
    float mu  = MS[(size_t)b * 1024 + t];
    float sig = MS[(size_t)b * 1024 + 512 + t];
    float inv = -0.5f * __builtin_amdgcn_rcpf(fmaf(sig, sig, EPS_SIG));
    float acc = 0.f;
    #pragma unroll
    for (int k = 0; k < 8; ++k) {
        float d = gs[k][t] - mu;
        acc = fmaf(__expf(d * d * inv), cs[k][t], acc);
    }
    const size_t idx = (size_t)b * TT + t;
    float qn = Q[idx] + acc;
    Q[idx] = qn;
    // ---- block LN over the 512 values (one per thread) ----
    const int wid = tid >> 6, lane = tid & 63;
    float s = qn;
    #pragma unroll
    for (int off = 32; off > 0; off >>= 1) s += __shfl_down(s, off);
    if (lane == 0) red[0][wid] = s;
    __syncthreads();
    float tot = 0.f;
    #pragma unroll
    for (int w = 0; w < 8; ++w) tot += red[0][w];
    float mean = tot * (1.0f / TT);
    float d = qn - mean;
    float ss = d * d;
    #pragma unroll
    for (int off = 32; off > 0; off >>= 1) ss += __shfl_down(ss, off);
    if (lane == 0) red[1][wid] = ss;
    __syncthreads();
    float vtot = 0.f;
    #pragma unroll
    for (int w = 0; w < 8; ++w) vtot += red[1][w];
    float rstd = rsqrtf(vtot * (1.0f / TT) + EPS_LN);
    Y[idx] = (_Float16)(d * rstd * g[t] + bia[t]);
}

// ---------------- readout: out[b] = silu(Q[b,:]) . ro_w + ro_b ----------------
__global__ __launch_bounds__(256) void readout_kernel(
    const float* __restrict__ Q, const float* __restrict__ row_,
    const float* __restrict__ rob, float* __restrict__ out) {
    int lane = threadIdx.x & 63;
    int row  = blockIdx.x * 4 + (threadIdx.x >> 6);
    const float* qr = Q + (size_t)row * TT;
    float acc = 0.f;
    #pragma unroll
    for (int i = 0; i < 8; ++i) {
        int t = lane * 8 + i;
        acc = fmaf(silu_f(qr[t]), row_[t], acc);
    }
    #pragma unroll
    for (int off = 32; off > 0; off >>= 1) acc += __shfl_down(acc, off);
    if (lane == 0) out[row] = acc + rob[0];
}

} // namespace

extern "C" void kernel_launch(void* const* d_in, const int* in_sizes, int n_in,
                              void* d_out, int out_size, void* d_ws, size_t ws_size,
                              hipStream_t stream) {
    const float* x     = (const float*)d_in[0];
    const float* omega = (const float*)d_in[1];
    const float* G     = (const float*)d_in[2];
    const float* phase = (const float*)d_in[3];
    const float* l1_w  = (const float*)d_in[4];
    const float* l1_b  = (const float*)d_in[5];
    const float* mu_w  = (const float*)d_in[6];
    const float* mu_b  = (const float*)d_in[7];
    const float* sg_w  = (const float*)d_in[8];
    const float* sg_b  = (const float*)d_in[9];
    const float* alqg  = (const float*)d_in[10];
    const float* alqb  = (const float*)d_in[11];
    const float* alfg  = (const float*)d_in[12];
    const float* alfb  = (const float*)d_in[13];
    const float* a_w1  = (const float*)d_in[14];
    const float* a_b1  = (const float*)d_in[15];
    const float* a_w2  = (const float*)d_in[16];
    const float* a_b2  = (const float*)d_in[17];
    const float* mln_g = (const float*)d_in[18];
    const float* mln_b = (const float*)d_in[19];
    const float* m_w1  = (const float*)d_in[20];
    const float* m_b1  = (const float*)d_in[21];
    const float* m_w2  = (const float*)d_in[22];
    const float* m_b2  = (const float*)d_in[23];
    const float* ro_w  = (const float*)d_in[24];
    const float* ro_b  = (const float*)d_in[25];

    // ---- workspace layout (total 100,663,296 B == round-1 proven footprint) ----
    char* ws = (char*)d_ws;
    float*     Q    = (float*)ws;                          // 16 MB  [B,T] fp32
    _Float16*  h_hi = (_Float16*)(ws + 16777216);          //  8 MB  [B,T] f16
    _Float16*  h_lo = (_Float16*)(ws + 25165824);          //  8 MB  [B,T] f16
    _Float16*  mid  = (_Float16*)(ws + 33554432);          // 32 MB  [B,F] f16
    float*     MS   = (float*)(ws + 33554432);             // alias on mid: [B,1024] fp32
    _Float16*  wbuf = (_Float16*)(ws + 67108864);          // 32 MB  f16 weights

    _Float16* msw_hi = wbuf;                     // 4*1024*512 (mu/sig concat)
    _Float16* msw_lo = msw_hi + 2097152;
    _Float16* aw1    = msw_lo + 2097152;         // 4*2048*512
    _Float16* aw2    = aw1 + 4194304;
    _Float16* mw1    = aw2 + 4194304;            // 2*2048*512
    _Float16* mw2    = mw1 + 2097152;

    dim3 blk(256);
    const int BIG = 1 << 30;

    // weight conversion (re-done every call; inputs are re-poisoned by harness)
    cvtcat_kernel<<<1024, blk, 0, stream>>>(mu_w, msw_hi, msw_lo, 0);
    cvtcat_kernel<<<1024, blk, 0, stream>>>(sg_w, msw_hi, msw_lo, 262144);
    cvt_kernel<false><<<4096, blk, 0, stream>>>(a_w1, aw1, nullptr, 4194304);
    cvt_kernel<false><<<4096, blk, 0, stream>>>(a_w2, aw2, nullptr, 4194304);
    cvt_kernel<false><<<2048, blk, 0, stream>>>(m_w1, mw1, nullptr, 2097152);
    cvt_kernel<false><<<2048, blk, 0, stream>>>(m_w2, mw2, nullptr, 2097152);

    tok_kernel<<<BB * TT / 256, blk, 0, stream>>>(x, l1_w, l1_b, Q);

    for (int i = 0; i < 4; ++i) {
        ln_kernel<true><<<BB / 4, blk, 0, stream>>>(
            Q, alqg + i * TT, alqb + i * TT, h_hi, h_lo);
        // fused mu|sig SPLIT GEMM: N=1024, deep pipeline, tanh on mu half only
        gemmdp_kernel<256, 128, 2, 4, 3, true, 3, false, float>
            <<<dim3(BB / 256, 1024 / 128), dim3(512), 0, stream>>>(
            h_hi, h_lo, msw_hi + (size_t)i * 524288, msw_lo + (size_t)i * 524288,
            mu_b + i * TT, sg_b + i * TT, nullptr, MS, 1024, TT, TT);
        // fused attention update + LN -> h_hi
        attnln_kernel<<<BB, dim3(512), 0, stream>>>(
            Q, MS, x, omega, G, phase, alfg + i * TT, alfb + i * TT, h_hi);
        gemmdp_kernel<256, 256, 2, 4, 4, false, 1, false, _Float16>
            <<<dim3(BB / 256, FF / 256), dim3(512), 0, stream>>>(
            h_hi, nullptr, aw1 + (size_t)i * 1048576, nullptr,
            a_b1 + i * FF, a_b1 + i * FF, nullptr, mid, FF, TT, BIG);
        gemmdp_kernel<128, 128, 2, 4, 4, false, 0, true, float>
            <<<dim3(BB / 128, TT / 128), dim3(512), 0, stream>>>(
            mid, nullptr, aw2 + (size_t)i * 1048576, nullptr,
            a_b2 + i * TT, a_b2 + i * TT, Q, Q, TT, FF, BIG);
    }
    for (int i = 0; i < 2; ++i) {
        ln_kernel<false><<<BB / 4, blk, 0, stream>>>(
            Q, mln_g + i * TT, mln_b + i * TT, h_hi, nullptr);
        gemmdp_kernel<256, 256, 2, 4, 4, false, 1, false, _Float16>
            <<<dim3(BB / 256, FF / 256), dim3(512), 0, stream>>>(
            h_hi, nullptr, mw1 + (size_t)i * 1048576, nullptr,
            m_b1 + i * FF, m_b1 + i * FF, nullptr, mid, FF, TT, BIG);
        gemmdp_kernel<128, 128, 2, 4, 4, false, 0, true, float>
            <<<dim3(BB / 128, TT / 128), dim3(512), 0, stream>>>(
            mid, nullptr, mw2 + (size_t)i * 1048576, nullptr,
            m_b2 + i * TT, m_b2 + i * TT, Q, Q, TT, FF, BIG);
    }

    readout_kernel<<<BB / 4, blk, 0, stream>>>(Q, ro_w, ro_b, (float*)d_out);
}

// Round 6
// 766.769 us; speedup vs baseline: 1.2415x; 1.0235x over previous
//
#include <hip/hip_runtime.h>
#include <cmath>

namespace {

constexpr int BB = 8192;
constexpr int TT = 512;
constexpr int FF = 2048;
constexpr float EPS_LN  = 1e-5f;
constexpr float EPS_SIG = 1e-8f;

typedef _Float16 half8 __attribute__((ext_vector_type(8)));
typedef _Float16 half4 __attribute__((ext_vector_type(4)));
typedef float f32x4 __attribute__((ext_vector_type(4)));

typedef __attribute__((address_space(1))) void gvoid_t;
typedef __attribute__((address_space(3))) void lvoid_t;

__device__ __forceinline__ void async16(void* lds, const void* g) {
    __builtin_amdgcn_global_load_lds((gvoid_t*)g, (lvoid_t*)lds, 16, 0, 0);
}

__device__ __forceinline__ float silu_f(float v) {
    return v / (1.0f + expf(-v));
}
// fast silu: only for f16-rounded outputs (error ~1e-6 << f16 ulp)
__device__ __forceinline__ float silu_fast(float v) {
    return v * __builtin_amdgcn_rcpf(1.0f + __expf(-v));
}

// ------------- fp32 -> f16 (hi, optional lo residual) weight conversion -------------
template <bool LO>
__global__ __launch_bounds__(256) void cvt_kernel(
    const float* __restrict__ s, _Float16* __restrict__ hi,
    _Float16* __restrict__ lo, int n) {
    int i = (blockIdx.x * 256 + threadIdx.x) * 4;
    if (i >= n) return;
    float4 v = *(const float4*)(s + i);
    half4 h;
    h[0] = (_Float16)v.x; h[1] = (_Float16)v.y;
    h[2] = (_Float16)v.z; h[3] = (_Float16)v.w;
    *(half4*)(hi + i) = h;
    if (LO) {
        half4 l;
        l[0] = (_Float16)(v.x - (float)h[0]);
        l[1] = (_Float16)(v.y - (float)h[1]);
        l[2] = (_Float16)(v.z - (float)h[2]);
        l[3] = (_Float16)(v.w - (float)h[3]);
        *(half4*)(lo + i) = l;
    }
}

// ---- cvt into mu/sig-concatenated layout: src [4][512][512] -> dst [4][1024][512]+base ----
__global__ __launch_bounds__(256) void cvtcat_kernel(
    const float* __restrict__ s, _Float16* __restrict__ hi,
    _Float16* __restrict__ lo, int base) {
    int i = (blockIdx.x * 256 + threadIdx.x) * 4;          // < 4*512*512
    int dst = ((i >> 18) << 19) + base + (i & 262143);
    float4 v = *(const float4*)(s + i);
    half4 h, l;
    h[0] = (_Float16)v.x; h[1] = (_Float16)v.y;
    h[2] = (_Float16)v.z; h[3] = (_Float16)v.w;
    l[0] = (_Float16)(v.x - (float)h[0]);
    l[1] = (_Float16)(v.y - (float)h[1]);
    l[2] = (_Float16)(v.z - (float)h[2]);
    l[3] = (_Float16)(v.w - (float)h[3]);
    *(half4*)(hi + dst) = h;
    *(half4*)(lo + dst) = l;
}

// ---------------- tokenizer: Q[b,t] = silu(x . l1_w[t] + l1_b[t]) ----------------
__global__ __launch_bounds__(256) void tok_kernel(
    const float* __restrict__ x, const float* __restrict__ l1w,
    const float* __restrict__ l1b, float* __restrict__ Q) {
    int idx = blockIdx.x * 256 + threadIdx.x;          // < B*T
    int b = idx >> 9, t = idx & 511;
    float x0 = x[2 * b], x1 = x[2 * b + 1];
    float v = fmaf(x0, l1w[2 * t], fmaf(x1, l1w[2 * t + 1], l1b[t]));
    Q[idx] = silu_f(v);
}

// ------- layernorm (fp32 in, f16 out, optional f16 lo residual), wave per row -------
template <bool LO>
__global__ __launch_bounds__(256) void ln_kernel(
    const float* __restrict__ X, const float* __restrict__ g,
    const float* __restrict__ bia, _Float16* __restrict__ Y,
    _Float16* __restrict__ Ylo) {
    int lane = threadIdx.x & 63;
    int row  = blockIdx.x * 4 + (threadIdx.x >> 6);
    const float* xr = X + (size_t)row * TT;
    float v[8];
    {
        float4 a = *(const float4*)(xr + lane * 8);
        float4 c = *(const float4*)(xr + lane * 8 + 4);
        v[0]=a.x; v[1]=a.y; v[2]=a.z; v[3]=a.w;
        v[4]=c.x; v[5]=c.y; v[6]=c.z; v[7]=c.w;
    }
    float s = 0.f;
    #pragma unroll
    for (int i = 0; i < 8; ++i) s += v[i];
    #pragma unroll
    for (int off = 32; off > 0; off >>= 1) s += __shfl_down(s, off);
    float mean = __shfl(s, 0) * (1.0f / TT);
    float ss = 0.f;
    #pragma unroll
    for (int i = 0; i < 8; ++i) { float d = v[i] - mean; ss = fmaf(d, d, ss); }
    #pragma unroll
    for (int off = 32; off > 0; off >>= 1) ss += __shfl_down(ss, off);
    float var  = __shfl(ss, 0) * (1.0f / TT);
    float rstd = rsqrtf(var + EPS_LN);
    half8 hv, lv;
    #pragma unroll
    for (int i = 0; i < 8; ++i) {
        int t = lane * 8 + i;
        float o = (v[i] - mean) * rstd * g[t] + bia[t];
        hv[i] = (_Float16)o;
        if (LO) lv[i] = (_Float16)(o - (float)hv[i]);
    }
    *(half8*)(Y + (size_t)row * TT + lane * 8) = hv;
    if (LO) *(half8*)(Ylo + (size_t)row * TT + lane * 8) = lv;
}

// ========== unified deep-pipelined MFMA GEMM (T3+T4+T5): C = act(A@W^T + b) (+R) =====
// Tile BM x BN, WGM x WGN waves (wave tile (BM/WGM) x (BN/WGN)), BK=32, mfma 16x16x32.
// LDS ring of NBUF K-tile buffers; D=NBUF-1 tiles in flight; steady-state counted
// s_waitcnt vmcnt((D-1)*LPT) -- NEVER drained in the main loop; ONE raw s_barrier
// per K-iter; setprio(1) around the MFMA cluster.
// MINW = min waves/EU for __launch_bounds__: MINW=4 with LDS<=80KB forces VGPR<=128
// -> 2 blocks/CU so a second block fills the barrier/vmcnt stalls (m114 overlap).
// Source-side XOR chunk swizzle -> conflict-free ds_read_b128 (0 conflicts R0-R5).
// SPLIT: acc = A@W + Alo@W + A@Wlo (near-fp32 from f16 inputs).
// ACT: 0=none, 1=silu_fast, 3=tanh for cols<nsplit else none (fused mu|sig).
// bias: cols<nsplit from bias[], else bias2[col-nsplit] (block-uniform select).
template <int BM, int BN, int WGM, int WGN, int NBUF, int MINW, bool SPLIT,
          int ACT, bool RESID, typename OutT>
__global__ __launch_bounds__(WGM * WGN * 64, MINW) void gemmdp_kernel(
    const _Float16* __restrict__ A, const _Float16* __restrict__ Alo,
    const _Float16* __restrict__ W, const _Float16* __restrict__ Wlo,
    const float* __restrict__ bias, const float* __restrict__ bias2,
    const float* __restrict__ R, OutT* __restrict__ C,
    int N, int K, int nsplit) {
    constexpr int BK      = 32;                    // halves per K-tile
    constexpr int THREADS = WGM * WGN * 64;
    constexpr int NS   = SPLIT ? 2 : 1;
    constexpr int D    = NBUF - 1;
    constexpr int CH_A = NS * BM * 4;              // 16B chunks of A per tile
    constexpr int CH_T = NS * (BM + BN) * 4;
    constexpr int LPT  = CH_T / THREADS;           // loads/thread/tile
    static_assert(CH_T % THREADS == 0 && CH_A % THREADS == 0, "staging split");
    constexpr int ABUF = NS * BM * BK;             // halves per buf (A region)
    constexpr int WBUF = NS * BN * BK;
    constexpr int WOFF = NBUF * ABUF;              // W region base
    constexpr int WTM  = BM / WGM;
    constexpr int WTN  = BN / WGN;
    constexpr int MI   = WTM / 16;
    constexpr int NI   = WTN / 16;

    __shared__ alignas(16) _Float16 lds[NBUF * (ABUF + WBUF)];

    const int tid = threadIdx.x;
    const int m0  = blockIdx.x * BM;
    const int n0  = blockIdx.y * BN;

    const _Float16* Asrc[2] = {A, Alo};
    const _Float16* Wsrc[2] = {W, Wlo};

    // ---- staging plan (fully unrolled -> registers; per-j branch is uniform) ----
    const _Float16* gsrc[LPT];
    int off0[LPT], bstr[LPT];
    #pragma unroll
    for (int j = 0; j < LPT; ++j) {
        int idx = j * THREADS + tid;
        if (j * THREADS < CH_A) {                  // A chunk (compile-time per j)
            int s   = idx / (BM * 4);
            int rc  = idx % (BM * 4);
            int row = rc >> 2, sl = rc & 3;
            int src = sl ^ ((row >> 1) & 3);
            gsrc[j] = Asrc[s] + (size_t)(m0 + row) * K + src * 8;
            off0[j] = (s * BM + row) * BK + sl * 8;
            bstr[j] = ABUF;
        } else {                                   // W chunk
            int i2  = idx - CH_A;
            int s   = i2 / (BN * 4);
            int rc  = i2 % (BN * 4);
            int row = rc >> 2, sl = rc & 3;
            int src = sl ^ ((row >> 1) & 3);
            gsrc[j] = Wsrc[s] + (size_t)(n0 + row) * K + src * 8;
            off0[j] = WOFF + (s * BN + row) * BK + sl * 8;
            bstr[j] = WBUF;
        }
    }

    auto stage = [&](int buf, int k0) {
        #pragma unroll
        for (int j = 0; j < LPT; ++j)
            async16(&lds[off0[j] + buf * bstr[j]], gsrc[j] + k0);
    };

    // ---- fragment geometry ----
    const int wid  = tid >> 6;
    const int wr   = wid / WGN;
    const int wc   = wid % WGN;
    const int lane = tid & 63;
    const int fr   = lane & 15;
    const int q    = lane >> 4;
    const int swz  = (q ^ ((fr >> 1) & 3)) * 8;    // swizzled k-offset (halves)

    const f32x4 vzero = {0.f, 0.f, 0.f, 0.f};
    f32x4 acc[MI][NI];
    #pragma unroll
    for (int mi = 0; mi < MI; ++mi)
        #pragma unroll
        for (int ni = 0; ni < NI; ++ni) acc[mi][ni] = vzero;

    auto body = [&](int buf) {
        const int da = buf * ABUF;
        const int dw = WOFF + buf * WBUF;
        half8 a[NS][MI], b[NS][NI];
        #pragma unroll
        for (int s = 0; s < NS; ++s) {
            #pragma unroll
            for (int mi = 0; mi < MI; ++mi)
                a[s][mi] = *(const half8*)&lds[da + (s * BM + wr * WTM + mi * 16 + fr) * BK + swz];
            #pragma unroll
            for (int ni = 0; ni < NI; ++ni)
                b[s][ni] = *(const half8*)&lds[dw + (s * BN + wc * WTN + ni * 16 + fr) * BK + swz];
        }
        __builtin_amdgcn_s_setprio(1);
        #pragma unroll
        for (int mi = 0; mi < MI; ++mi)
            #pragma unroll
            for (int ni = 0; ni < NI; ++ni)
                acc[mi][ni] = __builtin_amdgcn_mfma_f32_16x16x32_f16(
                    a[0][mi], b[0][ni], acc[mi][ni], 0, 0, 0);
        if (SPLIT) {
            #pragma unroll
            for (int mi = 0; mi < MI; ++mi)
                #pragma unroll
                for (int ni = 0; ni < NI; ++ni)
                    acc[mi][ni] = __builtin_amdgcn_mfma_f32_16x16x32_f16(
                        a[1][mi], b[0][ni], acc[mi][ni], 0, 0, 0);
            #pragma unroll
            for (int mi = 0; mi < MI; ++mi)
                #pragma unroll
                for (int ni = 0; ni < NI; ++ni)
                    acc[mi][ni] = __builtin_amdgcn_mfma_f32_16x16x32_f16(
                        a[0][mi], b[1][ni], acc[mi][ni], 0, 0, 0);
        }
        __builtin_amdgcn_s_setprio(0);
    };

    const int NK = K / BK;                          // 16 (K=512) or 64 (K=2048)

    #pragma unroll
    for (int s = 0; s < D; ++s) stage(s, s * BK);

    int rbuf = 0, sbuf = D;
    for (int ki = 0; ki < NK - D; ++ki) {
        asm volatile("s_waitcnt vmcnt(%0)" :: "n"((D - 1) * LPT) : "memory");
        __builtin_amdgcn_s_barrier();
        asm volatile("" ::: "memory");
        stage(sbuf, (ki + D) * BK);
        sbuf = (sbuf + 1 == NBUF) ? 0 : sbuf + 1;
        body(rbuf);
        rbuf = (rbuf + 1 == NBUF) ? 0 : rbuf + 1;
    }
    if constexpr (D >= 3) {
        asm volatile("s_waitcnt vmcnt(%0)" :: "n"(2 * LPT) : "memory");
        __builtin_amdgcn_s_barrier();
        asm volatile("" ::: "memory");
        body(rbuf);
        rbuf = (rbuf + 1 == NBUF) ? 0 : rbuf + 1;
    }
    if constexpr (D >= 2) {
        asm volatile("s_waitcnt vmcnt(%0)" :: "n"(1 * LPT) : "memory");
        __builtin_amdgcn_s_barrier();
        asm volatile("" ::: "memory");
        body(rbuf);
        rbuf = (rbuf + 1 == NBUF) ? 0 : rbuf + 1;
    }
    asm volatile("s_waitcnt vmcnt(0)" ::: "memory");
    __builtin_amdgcn_s_barrier();
    asm volatile("" ::: "memory");
    body(rbuf);

    // ---- epilogue; C/D layout: col = lane&15, row = (lane>>4)*4 + reg ----
    const bool fh = (n0 < nsplit);                  // block-uniform half select
    const float* bp = fh ? bias : bias2;
    const int coff = fh ? 0 : nsplit;
    const int r0 = q * 4;
    #pragma unroll
    for (int mi = 0; mi < MI; ++mi) {
        #pragma unroll
        for (int ni = 0; ni < NI; ++ni) {
            const int col = n0 + wc * WTN + ni * 16 + fr;
            const float bv = bp[col - coff];
            #pragma unroll
            for (int r = 0; r < 4; ++r) {
                const int row = m0 + wr * WTM + mi * 16 + r0 + r;
                float v = acc[mi][ni][r] + bv;
                if (ACT == 1) v = silu_fast(v);
                if (ACT == 3 && fh) v = tanhf(v);
                if (RESID) v += R[(size_t)row * N + col];
                C[(size_t)row * N + col] = (OutT)v;
            }
        }
    }
}

// ==== fused attention update + layernorm: Q += sum_k S*H; h = LN(Q)*g+b -> f16 ====
// One block per batch row b, 512 threads = one token each. MS is the fused [B,1024]
// mu|sig buffer. After the update, block-wide two-pass LN (wave shuffle + 8-slot
// LDS cross-wave reduce) emits h_hi directly -- saves the separate ln dispatch and
// its 16MB Q re-read.
__global__ __launch_bounds__(512) void attnln_kernel(
    float* __restrict__ Q, const float* __restrict__ MS,
    const float* __restrict__ x,
    const float* __restrict__ omega, const float* __restrict__ G,
    const float* __restrict__ phase,
    const float* __restrict__ g, const float* __restrict__ bia,
    _Float16* __restrict__ Y) {
    __shared__ float cs[8][516];
    __shared__ float gs[8][516];
    __shared__ float red[2][8];
    const int tid = threadIdx.x;
    const int b   = blockIdx.x;
    const float x0 = x[2 * b], x1 = x[2 * b + 1];
    #pragma unroll
    for (int it = 0; it < 8; ++it) {
        int j = it * 512 + tid;            // 0..4095 flat (t,k) index
        float2 om = *(const float2*)(omega + 2 * j);
        float arg = fmaf(om.x, x0, fmaf(om.y, x1, phase[j]));
        cs[j & 7][j >> 3] = __cosf(arg);
        gs[j & 7][j >> 3] = G[j];
    }
    __syncthreads();
    const int t = tid;
    float mu  = MS[(size_t)b * 1024 + t];
    float sig = MS[(size_t)b * 1024 + 512 + t];
    float inv = -0.5f * __builtin_amdgcn_rcpf(fmaf(sig, sig, EPS_SIG));
    float acc = 0.f;
    #pragma unroll
    for (int k = 0; k < 8; ++k) {
        float d = gs[k][t] - mu;
        acc = fmaf(__expf(d * d * inv), cs[k][t], acc);
    }
    const size_t idx = (size_t)b * TT + t;
    float qn = Q[idx] + acc;
    Q[idx] = qn;
    // ---- block LN over the 512 values (one per thread) ----
    const int wid = tid >> 6, lane = tid & 63;
    float s = qn;
    #pragma unroll
    for (int off = 32; off > 0; off >>= 1) s += __shfl_down(s, off);
    if (lane == 0) red[0][wid] = s;
    __syncthreads();
    float tot = 0.f;
    #pragma unroll
    for (int w = 0; w < 8; ++w) tot += red[0][w];
    float mean = tot * (1.0f / TT);
    float d = qn - mean;
    float ss = d * d;
    #pragma unroll
    for (int off = 32; off > 0; off >>= 1) ss += __shfl_down(ss, off);
    if (lane == 0) red[1][wid] = ss;
    __syncthreads();
    float vtot = 0.f;
    #pragma unroll
    for (int w = 0; w < 8; ++w) vtot += red[1][w];
    float rstd = rsqrtf(vtot * (1.0f / TT) + EPS_LN);
    Y[idx] = (_Float16)(d * rstd * g[t] + bia[t]);
}

// ---------------- readout: out[b] = silu(Q[b,:]) . ro_w + ro_b ----------------
__global__ __launch_bounds__(256) void readout_kernel(
    const float* __restrict__ Q, const float* __restrict__ row_,
    const float* __restrict__ rob, float* __restrict__ out) {
    int lane = threadIdx.x & 63;
    int row  = blockIdx.x * 4 + (threadIdx.x >> 6);
    const float* qr = Q + (size_t)row * TT;
    float acc = 0.f;
    #pragma unroll
    for (int i = 0; i < 8; ++i) {
        int t = lane * 8 + i;
        acc = fmaf(silu_f(qr[t]), row_[t], acc);
    }
    #pragma unroll
    for (int off = 32; off > 0; off >>= 1) acc += __shfl_down(acc, off);
    if (lane == 0) out[row] = acc + rob[0];
}

} // namespace

extern "C" void kernel_launch(void* const* d_in, const int* in_sizes, int n_in,
                              void* d_out, int out_size, void* d_ws, size_t ws_size,
                              hipStream_t stream) {
    const float* x     = (const float*)d_in[0];
    const float* omega = (const float*)d_in[1];
    const float* G     = (const float*)d_in[2];
    const float* phase = (const float*)d_in[3];
    const float* l1_w  = (const float*)d_in[4];
    const float* l1_b  = (const float*)d_in[5];
    const float* mu_w  = (const float*)d_in[6];
    const float* mu_b  = (const float*)d_in[7];
    const float* sg_w  = (const float*)d_in[8];
    const float* sg_b  = (const float*)d_in[9];
    const float* alqg  = (const float*)d_in[10];
    const float* alqb  = (const float*)d_in[11];
    const float* alfg  = (const float*)d_in[12];
    const float* alfb  = (const float*)d_in[13];
    const float* a_w1  = (const float*)d_in[14];
    const float* a_b1  = (const float*)d_in[15];
    const float* a_w2  = (const float*)d_in[16];
    const float* a_b2  = (const float*)d_in[17];
    const float* mln_g = (const float*)d_in[18];
    const float* mln_b = (const float*)d_in[19];
    const float* m_w1  = (const float*)d_in[20];
    const float* m_b1  = (const float*)d_in[21];
    const float* m_w2  = (const float*)d_in[22];
    const float* m_b2  = (const float*)d_in[23];
    const float* ro_w  = (const float*)d_in[24];
    const float* ro_b  = (const float*)d_in[25];

    // ---- workspace layout (total 100,663,296 B == round-1 proven footprint) ----
    char* ws = (char*)d_ws;
    float*     Q    = (float*)ws;                          // 16 MB  [B,T] fp32
    _Float16*  h_hi = (_Float16*)(ws + 16777216);          //  8 MB  [B,T] f16
    _Float16*  h_lo = (_Float16*)(ws + 25165824);          //  8 MB  [B,T] f16
    _Float16*  mid  = (_Float16*)(ws + 33554432);          // 32 MB  [B,F] f16
    float*     MS   = (float*)(ws + 33554432);             // alias on mid: [B,1024] fp32
    _Float16*  wbuf = (_Float16*)(ws + 67108864);          // 32 MB  f16 weights

    _Float16* msw_hi = wbuf;                     // 4*1024*512 (mu/sig concat)
    _Float16* msw_lo = msw_hi + 2097152;
    _Float16* aw1    = msw_lo + 2097152;         // 4*2048*512
    _Float16* aw2    = aw1 + 4194304;
    _Float16* mw1    = aw2 + 4194304;            // 2*2048*512
    _Float16* mw2    = mw1 + 2097152;

    dim3 blk(256);
    const int BIG = 1 << 30;

    // weight conversion (re-done every call; inputs are re-poisoned by harness)
    cvtcat_kernel<<<1024, blk, 0, stream>>>(mu_w, msw_hi, msw_lo, 0);
    cvtcat_kernel<<<1024, blk, 0, stream>>>(sg_w, msw_hi, msw_lo, 262144);
    cvt_kernel<false><<<4096, blk, 0, stream>>>(a_w1, aw1, nullptr, 4194304);
    cvt_kernel<false><<<4096, blk, 0, stream>>>(a_w2, aw2, nullptr, 4194304);
    cvt_kernel<false><<<2048, blk, 0, stream>>>(m_w1, mw1, nullptr, 2097152);
    cvt_kernel<false><<<2048, blk, 0, stream>>>(m_w2, mw2, nullptr, 2097152);

    tok_kernel<<<BB * TT / 256, blk, 0, stream>>>(x, l1_w, l1_b, Q);

    for (int i = 0; i < 4; ++i) {
        ln_kernel<true><<<BB / 4, blk, 0, stream>>>(
            Q, alqg + i * TT, alqb + i * TT, h_hi, h_lo);
        // fused mu|sig SPLIT GEMM: N=1024, deep pipeline, tanh on mu half only
        gemmdp_kernel<256, 128, 4, 2, 3, 2, true, 3, false, float>
            <<<dim3(BB / 256, 1024 / 128), dim3(512), 0, stream>>>(
            h_hi, h_lo, msw_hi + (size_t)i * 524288, msw_lo + (size_t)i * 524288,
            mu_b + i * TT, sg_b + i * TT, nullptr, MS, 1024, TT, TT);
        // fused attention update + LN -> h_hi
        attnln_kernel<<<BB, dim3(512), 0, stream>>>(
            Q, MS, x, omega, G, phase, alfg + i * TT, alfb + i * TT, h_hi);
        // w1: 256x128 tile, 72KB LDS, MINW=4 -> 2 blocks/CU
        gemmdp_kernel<256, 128, 4, 2, 3, 4, false, 1, false, _Float16>
            <<<dim3(BB / 256, FF / 128), dim3(512), 0, stream>>>(
            h_hi, nullptr, aw1 + (size_t)i * 1048576, nullptr,
            a_b1 + i * FF, a_b1 + i * FF, nullptr, mid, FF, TT, BIG);
        gemmdp_kernel<128, 128, 2, 4, 4, 4, false, 0, true, float>
            <<<dim3(BB / 128, TT / 128), dim3(512), 0, stream>>>(
            mid, nullptr, aw2 + (size_t)i * 1048576, nullptr,
            a_b2 + i * TT, a_b2 + i * TT, Q, Q, TT, FF, BIG);
    }
    for (int i = 0; i < 2; ++i) {
        ln_kernel<false><<<BB / 4, blk, 0, stream>>>(
            Q, mln_g + i * TT, mln_b + i * TT, h_hi, nullptr);
        gemmdp_kernel<256, 128, 4, 2, 3, 4, false, 1, false, _Float16>
            <<<dim3(BB / 256, FF / 128), dim3(512), 0, stream>>>(
            h_hi, nullptr, mw1 + (size_t)i * 1048576, nullptr,
            m_b1 + i * FF, m_b1 + i * FF, nullptr, mid, FF, TT, BIG);
        gemmdp_kernel<128, 128, 2, 4, 4, 4, false, 0, true, float>
            <<<dim3(BB / 128, TT / 128), dim3(512), 0, stream>>>(
            mid, nullptr, mw2 + (size_t)i * 1048576, nullptr,
            m_b2 + i * TT, m_b2 + i * TT, Q, Q, TT, FF, BIG);
    }

    readout_kernel<<<BB / 4, blk, 0, stream>>>(Q, ro_w, ro_b, (float*)d_out);
}